// Round 1
// baseline (2677.926 us; speedup 1.0000x reference)
//
#include <hip/hip_runtime.h>
#include <stdint.h>

using u16 = unsigned short;
using u32 = unsigned int;

typedef __attribute__((ext_vector_type(8))) short short8;
typedef __attribute__((ext_vector_type(4))) float f32x4;

#define MFMA16(a,b,c) __builtin_amdgcn_mfma_f32_16x16x32_bf16(a,b,c,0,0,0)

__device__ __forceinline__ u16 f2bf(float f){
  u32 u = __float_as_uint(f);
  u += 0x7fffu + ((u>>16)&1u);
  return (u16)(u>>16);
}
__device__ __forceinline__ float bf2f(u16 b){ return __uint_as_float(((u32)b)<<16); }

//------------------------------------------------------------------
// RMSNorm: f32 [T,1536] -> bf16 [T,1536]
__global__ __launch_bounds__(192) void k_rmsnorm(const float* __restrict__ x,
                                                 const float* __restrict__ w,
                                                 u16* __restrict__ o)
{
  int t = blockIdx.x, tid = threadIdx.x;
  const float* xr = x + (size_t)t*1536 + tid*8;
  f32x4 a = *(const f32x4*)xr;
  f32x4 b = *(const f32x4*)(xr+4);
  float ss = a[0]*a[0]+a[1]*a[1]+a[2]*a[2]+a[3]*a[3]
           + b[0]*b[0]+b[1]*b[1]+b[2]*b[2]+b[3]*b[3];
  #pragma unroll
  for (int m=1;m<64;m<<=1) ss += __shfl_xor(ss,m);
  __shared__ float red[3];
  if ((tid&63)==0) red[tid>>6]=ss;
  __syncthreads();
  float inv = rsqrtf((red[0]+red[1]+red[2])*(1.0f/1536.0f)+1e-6f);
  const float* wp = w + tid*8;
  f32x4 wa = *(const f32x4*)wp;
  f32x4 wb = *(const f32x4*)(wp+4);
  u16* op = o + (size_t)t*1536 + tid*8;
  #pragma unroll
  for (int j=0;j<4;++j) op[j]   = f2bf(a[j]*inv*wa[j]);
  #pragma unroll
  for (int j=0;j<4;++j) op[j+4] = f2bf(b[j]*inv*wb[j]);
}

//------------------------------------------------------------------
// Generic 128x128 GEMM, A bf16 (optionally row-gathered), B f32 row-major
// (cvt->bf16 during LDS staging, stored transposed [col][k]).
// 256 thr = 4 waves (2x2 of 64x64), mfma 16x16x32 bf16, BK=32.
// MODE 0: Cb = bf16(acc)
// MODE 1: Cf = resid + acc*0.22 (f32)
// MODE 2: dual-N: silu(acc_gate)*acc_up -> bf16 Cb (B cols col0 and col0+halfN)
// MODE 3: Cf = acc (f32)
// MODE 4: atomicAdd(Cf[toks[row]], acc*gates[row])
template<int MODE, int GATHER>
__global__ __launch_bounds__(256,1) void k_gemm(
    const u16* __restrict__ A, int lda,
    const float* __restrict__ Bsrc, int ldb, long strideB, int K,
    int Mfix, const int* __restrict__ cnts, const int* __restrict__ offs,
    const int* __restrict__ toks, const float* __restrict__ gates,
    int halfN,
    u16* __restrict__ Cb, int ldcb,
    float* __restrict__ Cf, int ldcf,
    const float* __restrict__ resid)
{
  int e = blockIdx.z;
  int M = cnts ? cnts[e] : Mfix;
  int m0 = blockIdx.y*128;
  if (m0 >= M) return;
  int roff = offs ? offs[e] : 0;
  const float* Bp = Bsrc + (long)e*strideB;
  int col0 = blockIdx.x*128;

  __shared__ u16 Ash[128*40];   // [row][k], +8 pad -> 2-way bank max
  __shared__ u16 Bsh[128*40];   // [col][k]
  __shared__ u16 Bsh2[128*40];

  int tid = threadIdx.x, wv = tid>>6, lane = tid&63;
  int lr = lane&15, lg = lane>>4;
  int wr = (wv>>1)*64, wc = (wv&1)*64;

  f32x4 acc[4][4];
  f32x4 acc2[4][4];
  #pragma unroll
  for (int m=0;m<4;++m)
    #pragma unroll
    for (int n=0;n<4;++n){
      acc[m][n] = (f32x4){0.f,0.f,0.f,0.f};
      if constexpr(MODE==2) acc2[m][n] = (f32x4){0.f,0.f,0.f,0.f};
    }

  int nk = K>>5;
  for (int kt=0; kt<nk; ++kt){
    int k0 = kt<<5;
    __syncthreads();
    // stage A tile 128x32 (bf16), zero-fill rows >= M
    #pragma unroll
    for (int i=0;i<2;++i){
      int c = tid + i*256;
      int row = c>>2, kc = (c&3)*8;
      int gr = m0 + row;
      short8 av = (short8){0,0,0,0,0,0,0,0};
      if (gr < M){
        int ar = GATHER ? toks[roff+gr] : (roff+gr);
        av = *(const short8*)&A[(long)ar*lda + k0 + kc];
      }
      *(short8*)&Ash[row*40 + kc] = av;
    }
    // stage B tile 32x128 f32 -> bf16, transposed
    #pragma unroll
    for (int i=0;i<4;++i){
      int c = tid + i*256;
      int kr = c>>5, c4 = (c&31)*4;
      const float* bp = Bp + (long)(k0+kr)*ldb + col0 + c4;
      f32x4 bv = *(const f32x4*)bp;
      #pragma unroll
      for (int j=0;j<4;++j) Bsh[(c4+j)*40 + kr] = f2bf(bv[j]);
      if constexpr(MODE==2){
        f32x4 bu = *(const f32x4*)(bp + halfN);
        #pragma unroll
        for (int j=0;j<4;++j) Bsh2[(c4+j)*40 + kr] = f2bf(bu[j]);
      }
    }
    __syncthreads();
    short8 af[4], b1[4], b2[4];
    #pragma unroll
    for (int m=0;m<4;++m) af[m] = *(const short8*)&Ash[(wr+m*16+lr)*40 + lg*8];
    #pragma unroll
    for (int n=0;n<4;++n) b1[n] = *(const short8*)&Bsh[(wc+n*16+lr)*40 + lg*8];
    if constexpr(MODE==2){
      #pragma unroll
      for (int n=0;n<4;++n) b2[n] = *(const short8*)&Bsh2[(wc+n*16+lr)*40 + lg*8];
    }
    #pragma unroll
    for (int m=0;m<4;++m)
      #pragma unroll
      for (int n=0;n<4;++n){
        acc[m][n] = MFMA16(af[m], b1[n], acc[m][n]);
        if constexpr(MODE==2) acc2[m][n] = MFMA16(af[m], b2[n], acc2[m][n]);
      }
  }

  #pragma unroll
  for (int m=0;m<4;++m)
    #pragma unroll
    for (int n=0;n<4;++n)
      #pragma unroll
      for (int rr=0;rr<4;++rr){
        int row = wr + m*16 + lg*4 + rr;   // C/D: col=lane&15, row=(lane>>4)*4+reg
        int gr = m0 + row;
        if (gr >= M) continue;
        int col = wc + n*16 + lr;
        float va = acc[m][n][rr];
        if constexpr(MODE==0){
          Cb[(long)(roff+gr)*ldcb + col0 + col] = f2bf(va);
        } else if constexpr(MODE==1){
          long idx = (long)gr*ldcf + col0 + col;
          Cf[idx] = resid[idx] + va*0.22f;
        } else if constexpr(MODE==2){
          float u = acc2[m][n][rr];
          float s = va/(1.f+__expf(-va))*u;
          Cb[(long)(roff+gr)*ldcb + col0 + col] = f2bf(s);
        } else if constexpr(MODE==3){
          Cf[(long)gr*ldcf + col0 + col] = va;
        } else {
          int tk = toks[roff+gr];
          float gt = gates[roff+gr];
          atomicAdd(&Cf[(long)tk*ldcf + col0 + col], va*gt);
        }
      }
}

//------------------------------------------------------------------
// RoPE in-place on q (T,24,64) and k (T,8,64), half=32, pairs (j, j+32)
__global__ __launch_bounds__(256) void k_rope(const int* __restrict__ pos,
    u16* __restrict__ qb, u16* __restrict__ kb)
{
  int gid = blockIdx.x*256 + threadIdx.x;   // T*1024
  int t = gid >> 10, p = gid & 1023;
  int j = p & 31;
  float invf = __expf(-(float)j * 0.28782313662425574f); // ln(10000)/32
  float ang = (float)pos[t] * invf;
  float sn, cs; __sincosf(ang, &sn, &cs);
  u16* base;
  if (p < 768) base = qb + (long)t*1536 + (p>>5)*64;
  else         base = kb + (long)t*512  + ((p-768)>>5)*64;
  float x1 = bf2f(base[j]), x2 = bf2f(base[j+32]);
  base[j]    = f2bf(x1*cs - x2*sn);
  base[j+32] = f2bf(x2*cs + x1*sn);
}

//------------------------------------------------------------------
// Causal flash attention, GQA 24q/8kv, hd=64. Block = 4 waves, 64 q rows
// (16/wave), KBLK=64. S = mfma(Qfrag, Krow-frag) -> C[q][k].
__global__ __launch_bounds__(256,2) void k_attn(const u16* __restrict__ qg,
    const u16* __restrict__ kg, const u16* __restrict__ vg,
    u16* __restrict__ og)
{
  int qt = blockIdx.x, h = blockIdx.y, kvh = h/3;
  int tid = threadIdx.x, wv = tid>>6, lane = tid&63;
  int lr = lane&15, lg = lane>>4;
  __shared__ u16 Ksh[64*72];      // [krow][d], +8 pad
  __shared__ u16 Vsh[64*72];      // transposed: [d][krow]
  __shared__ u16 Psh[4][16*72];   // per-wave [qrow][krow]
  int q0 = qt*64;
  int qrow = q0 + wv*16 + lr;
  short8 qf[2];
  #pragma unroll
  for (int c=0;c<2;++c)
    qf[c] = *(const short8*)&qg[(long)qrow*1536 + h*64 + c*32 + lg*8];

  float m_[4], l_[4];
  f32x4 Ot[4];
  #pragma unroll
  for (int r=0;r<4;++r){ m_[r]=-1e30f; l_[r]=0.f; }
  #pragma unroll
  for (int d=0;d<4;++d) Ot[d]=(f32x4){0.f,0.f,0.f,0.f};

  for (int kt=0; kt<=qt; ++kt){
    __syncthreads();
    #pragma unroll
    for (int i=0;i<2;++i){
      int c = tid + i*256;
      int row = c>>3, dc = (c&7)*8;
      long gb = (long)(kt*64+row)*512 + kvh*64 + dc;
      short8 kv8 = *(const short8*)&kg[gb];
      *(short8*)&Ksh[row*72 + dc] = kv8;
      short8 vv = *(const short8*)&vg[gb];
      #pragma unroll
      for (int j=0;j<8;++j) Vsh[(dc+j)*72 + row] = (u16)vv[j];
    }
    __syncthreads();

    f32x4 S[4];
    #pragma unroll
    for (int n=0;n<4;++n) S[n]=(f32x4){0.f,0.f,0.f,0.f};
    #pragma unroll
    for (int n=0;n<4;++n)
      #pragma unroll
      for (int c=0;c<2;++c){
        short8 kf = *(const short8*)&Ksh[(n*16+lr)*72 + c*32 + lg*8];
        S[n] = MFMA16(qf[c], kf, S[n]);
      }

    float rmax[4] = {-1e30f,-1e30f,-1e30f,-1e30f};
    bool diag = (kt==qt);
    #pragma unroll
    for (int n=0;n<4;++n)
      #pragma unroll
      for (int r=0;r<4;++r){
        float sv = S[n][r]*0.015625f;
        if (diag){
          int colg = kt*64 + n*16 + lr;
          int rowg = q0 + wv*16 + lg*4 + r;
          if (colg > rowg) sv = -1e30f;
        }
        S[n][r] = sv;
        rmax[r] = fmaxf(rmax[r], sv);
      }
    #pragma unroll
    for (int msk=1; msk<16; msk<<=1){
      #pragma unroll
      for (int r=0;r<4;++r) rmax[r] = fmaxf(rmax[r], __shfl_xor(rmax[r], msk));
    }
    float alpha[4], rsum[4]={0.f,0.f,0.f,0.f};
    #pragma unroll
    for (int r=0;r<4;++r){
      float mn = fmaxf(m_[r], rmax[r]);
      alpha[r] = __expf(m_[r]-mn);
      m_[r] = mn;
    }
    #pragma unroll
    for (int n=0;n<4;++n)
      #pragma unroll
      for (int r=0;r<4;++r){
        float pv = __expf(S[n][r]-m_[r]);
        S[n][r]=pv; rsum[r]+=pv;
      }
    #pragma unroll
    for (int msk=1; msk<16; msk<<=1){
      #pragma unroll
      for (int r=0;r<4;++r) rsum[r] += __shfl_xor(rsum[r], msk);
    }
    #pragma unroll
    for (int r=0;r<4;++r) l_[r] = l_[r]*alpha[r] + rsum[r];
    #pragma unroll
    for (int d=0;d<4;++d)
      #pragma unroll
      for (int r=0;r<4;++r) Ot[d][r] *= alpha[r];

    #pragma unroll
    for (int n=0;n<4;++n)
      #pragma unroll
      for (int r=0;r<4;++r)
        Psh[wv][(lg*4+r)*72 + n*16 + lr] = f2bf(S[n][r]);
    __syncthreads();

    #pragma unroll
    for (int c=0;c<2;++c){
      short8 pf = *(const short8*)&Psh[wv][lr*72 + c*32 + lg*8];
      #pragma unroll
      for (int d=0;d<4;++d){
        short8 vf = *(const short8*)&Vsh[(d*16+lr)*72 + c*32 + lg*8];
        Ot[d] = MFMA16(pf, vf, Ot[d]);
      }
    }
  }

  #pragma unroll
  for (int d=0;d<4;++d)
    #pragma unroll
    for (int r=0;r<4;++r){
      int t = q0 + wv*16 + lg*4 + r;
      og[(long)t*1536 + h*64 + d*16 + lr] = f2bf(Ot[d][r]/l_[r]);
    }
}

//------------------------------------------------------------------
// Router: logits = h2 @ rw (1536x32), serial top-8 + softmax on lane 0
__global__ __launch_bounds__(64) void k_router(const u16* __restrict__ h2,
    const float* __restrict__ rw, int* __restrict__ topi, float* __restrict__ gatev)
{
  int t = blockIdx.x, lane = threadIdx.x;
  int e = lane & 31, hf = lane >> 5;
  const u16* hr = h2 + (size_t)t*1536 + hf*768;
  const float* wp = rw + (long)hf*768*32 + e;
  float s = 0.f;
  for (int d=0; d<768; ++d)
    s += bf2f(hr[d]) * wp[(long)d*32];
  s += __shfl_xor(s, 32);
  __shared__ float lgt[32];
  if (lane < 32) lgt[e] = s;
  __syncthreads();
  if (lane==0){
    u32 msk=0; float tv[8]; int ti[8];
    for (int kk=0;kk<8;++kk){
      float best=-1e30f; int bi=0;
      for (int j2=0;j2<32;++j2)
        if (!((msk>>j2)&1u) && lgt[j2] > best){ best=lgt[j2]; bi=j2; }
      msk |= 1u<<bi; tv[kk]=best; ti[kk]=bi;
    }
    float mx = tv[0], ssum = 0.f, ge[8];
    for (int kk=0;kk<8;++kk){ ge[kk]=__expf(tv[kk]-mx); ssum+=ge[kk]; }
    float isum = 1.f/ssum;
    for (int kk=0;kk<8;++kk){ topi[t*8+kk]=ti[kk]; gatev[t*8+kk]=ge[kk]*isum; }
  }
}

__global__ void k_hist(const int* __restrict__ topi, int* __restrict__ cnt){
  int i = blockIdx.x*256 + threadIdx.x;
  if (i < 4096*8) atomicAdd(&cnt[topi[i]], 1);
}
__global__ void k_scan(const int* __restrict__ cnt, int* __restrict__ offs, int* __restrict__ cur){
  if (threadIdx.x==0 && blockIdx.x==0){
    int a=0;
    for (int e2=0;e2<32;++e2){ offs[e2]=a; cur[e2]=a; a+=cnt[e2]; }
  }
}
__global__ void k_scatter(const int* __restrict__ topi, const float* __restrict__ gatev,
    int* __restrict__ cur, int* __restrict__ toks, float* __restrict__ gts){
  int i = blockIdx.x*256 + threadIdx.x;
  if (i < 4096*8){
    int e2 = topi[i];
    int p = atomicAdd(&cur[e2], 1);
    toks[p] = i>>3;
    gts[p] = gatev[i];
  }
}
__global__ void k_final(const float* __restrict__ h2f, const float* __restrict__ acc,
                        float* __restrict__ out){
  int i = blockIdx.x*256 + threadIdx.x;
  f32x4 a = ((const f32x4*)h2f)[i];
  f32x4 b = ((const f32x4*)acc)[i];
  ((f32x4*)out)[i] = a + b*0.22f;
}

//------------------------------------------------------------------
extern "C" void kernel_launch(void* const* d_in, const int* in_sizes, int n_in,
                              void* d_out, int out_size, void* d_ws, size_t ws_size,
                              hipStream_t stream)
{
  const int*   positions = (const int*)  d_in[0];
  const float* hs   = (const float*)d_in[1];
  const float* ln1w = (const float*)d_in[2];
  const float* wq   = (const float*)d_in[3];
  const float* wk   = (const float*)d_in[4];
  const float* wv   = (const float*)d_in[5];
  const float* wo   = (const float*)d_in[6];
  const float* ln2w = (const float*)d_in[7];
  const float* rww  = (const float*)d_in[8];
  const float* wgu  = (const float*)d_in[9];
  const float* wdn  = (const float*)d_in[10];
  const float* sgu  = (const float*)d_in[11];
  const float* sdn  = (const float*)d_in[12];
  float* out = (float*)d_out;

  char* ws = (char*)d_ws;
  size_t off = 0;
  auto alloc = [&](size_t b)->void*{ void* p = ws + off; off += (b + 255) & ~(size_t)255; return p; };

  u16* hbf     = (u16*)alloc((size_t)4096*1536*2);   // ln1 out; later reused as h2 (ln2 out)
  u16* qkv     = (u16*)alloc((size_t)33554432);      // q|k|v|attn-out; later reused as moe act
  u16* qbf  = qkv;
  u16* kbf  = qkv + (size_t)4096*1536;
  u16* vbf  = kbf + (size_t)4096*512;
  u16* aout = vbf + (size_t)4096*512;
  u16* act_moe = qkv;                                // 32768 x 512 bf16 == same 33.5 MB
  float* moeacc = (float*)alloc((size_t)4096*1536*4);
  u16* act_sh  = (u16*)alloc((size_t)4096*1024*2);
  int*   topi  = (int*)  alloc(4096*8*4);
  float* gatev = (float*)alloc(4096*8*4);
  int*   toks  = (int*)  alloc(4096*8*4);
  float* gts   = (float*)alloc(4096*8*4);
  int*   cnt   = (int*)  alloc(512);
  int*   offs  = (int*)  alloc(512);
  int*   cur   = (int*)  alloc(512);
  float* hidden2 = out;    // residual after attention lives in d_out
  u16*   h2bf = hbf;

  // 1. ln1
  k_rmsnorm<<<4096,192,0,stream>>>(hs, ln1w, hbf);
  // 2-4. q/k/v projections
  k_gemm<0,0><<<dim3(12,32,1),256,0,stream>>>(hbf,1536, wq,1536,0,1536, 4096,nullptr,nullptr,nullptr,nullptr,0, qbf,1536, nullptr,0, nullptr);
  k_gemm<0,0><<<dim3(4,32,1), 256,0,stream>>>(hbf,1536, wk,512, 0,1536, 4096,nullptr,nullptr,nullptr,nullptr,0, kbf,512,  nullptr,0, nullptr);
  k_gemm<0,0><<<dim3(4,32,1), 256,0,stream>>>(hbf,1536, wv,512, 0,1536, 4096,nullptr,nullptr,nullptr,nullptr,0, vbf,512,  nullptr,0, nullptr);
  // 5. rope (q,k in place)
  k_rope<<<16384,256,0,stream>>>(positions, qbf, kbf);
  // 6. causal GQA flash attention
  k_attn<<<dim3(64,24,1),256,0,stream>>>(qbf, kbf, vbf, aout);
  // 7. o-proj + residual -> hidden2 (in d_out)
  k_gemm<1,0><<<dim3(12,32,1),256,0,stream>>>(aout,1536, wo,1536,0,1536, 4096,nullptr,nullptr,nullptr,nullptr,0, nullptr,0, hidden2,1536, hs);
  // 8. ln2
  k_rmsnorm<<<4096,192,0,stream>>>(hidden2, ln2w, h2bf);
  // 9. router + top-8
  k_router<<<4096,64,0,stream>>>(h2bf, rww, topi, gatev);
  // 10-13. expert grouping
  hipMemsetAsync(cnt, 0, 32*4, stream);
  k_hist<<<128,256,0,stream>>>(topi, cnt);
  k_scan<<<1,64,0,stream>>>(cnt, offs, cur);
  k_scatter<<<128,256,0,stream>>>(topi, gatev, cur, toks, gts);
  // 14. moe gate_up + silu*mul (gathered rows; act overlays dead q/k/v/attn buffers)
  k_gemm<2,1><<<dim3(4,32,32),256,0,stream>>>(h2bf,1536, wgu,1024,(long)1536*1024,1536, 0,cnt,offs,toks,nullptr, 512, act_moe,512, nullptr,0, nullptr);
  // 15. shared gate_up + silu*mul
  k_gemm<2,0><<<dim3(8,32,1),256,0,stream>>>(h2bf,1536, sgu,2048,0,1536, 4096,nullptr,nullptr,nullptr,nullptr, 1024, act_sh,1024, nullptr,0, nullptr);
  // 16. shared down -> moeacc (plain store, defines moeacc)
  k_gemm<3,0><<<dim3(12,32,1),256,0,stream>>>(act_sh,1024, sdn,1536,0,1024, 4096,nullptr,nullptr,nullptr,nullptr,0, nullptr,0, moeacc,1536, nullptr);
  // 17. moe down, gate-scaled atomic scatter-add into moeacc
  k_gemm<4,0><<<dim3(12,32,32),256,0,stream>>>(act_moe,512, wdn,1536,(long)512*1536,512, 0,cnt,offs,toks,gts, 0, nullptr,0, moeacc,1536, nullptr);
  // 18. out = hidden2 + 0.22*(moe+shared)
  k_final<<<6144,256,0,stream>>>(hidden2, moeacc, out);

  (void)in_sizes; (void)n_in; (void)out_size; (void)ws_size;
}

// Round 2
// 1413.790 us; speedup vs baseline: 1.8941x; 1.8941x over previous
//
#include <hip/hip_runtime.h>
#include <stdint.h>

using u16 = unsigned short;
using u32 = unsigned int;

typedef __attribute__((ext_vector_type(8))) short short8;
typedef __attribute__((ext_vector_type(4))) short short4v;
typedef __attribute__((ext_vector_type(4))) float f32x4;

#define MFMA16(a,b,c) __builtin_amdgcn_mfma_f32_16x16x32_bf16(a,b,c,0,0,0)

__device__ __forceinline__ u16 f2bf(float f){
  u32 u = __float_as_uint(f);
  u += 0x7fffu + ((u>>16)&1u);
  return (u16)(u>>16);
}
__device__ __forceinline__ float bf2f(u16 b){ return __uint_as_float(((u32)b)<<16); }

__device__ __forceinline__ void gload16(const void* g, void* l){
  __builtin_amdgcn_global_load_lds(
      (const __attribute__((address_space(1))) u32*)g,
      (__attribute__((address_space(3))) u32*)l, 16, 0, 0);
}

//------------------------------------------------------------------
// Weight prep: src f32 [K][N] -> dst bf16 [N][K]  (per blockIdx.z matrix)
__global__ __launch_bounds__(256) void k_wt(const float* __restrict__ src,
    u16* __restrict__ dst, int K, int N, long sstride, long dstride)
{
  __shared__ float tile[32][33];
  int nb = blockIdx.x*32, kb = blockIdx.y*32;
  const float* S = src + (long)blockIdx.z*sstride;
  u16* D = dst + (long)blockIdx.z*dstride;
  int tid = threadIdx.x;
  int r = tid>>3, c4 = (tid&7)*4;
  f32x4 v = *(const f32x4*)&S[(long)(kb+r)*N + nb + c4];
  tile[r][c4+0]=v[0]; tile[r][c4+1]=v[1]; tile[r][c4+2]=v[2]; tile[r][c4+3]=v[3];
  __syncthreads();
  short4v o;
  o[0]=(short)f2bf(tile[c4+0][r]);
  o[1]=(short)f2bf(tile[c4+1][r]);
  o[2]=(short)f2bf(tile[c4+2][r]);
  o[3]=(short)f2bf(tile[c4+3][r]);
  *(short4v*)&D[(long)(nb+r)*K + kb + c4] = o;
}

//------------------------------------------------------------------
// RMSNorm: f32 [T,1536] -> bf16 [T,1536]
__global__ __launch_bounds__(192) void k_rmsnorm(const float* __restrict__ x,
                                                 const float* __restrict__ w,
                                                 u16* __restrict__ o)
{
  int t = blockIdx.x, tid = threadIdx.x;
  const float* xr = x + (size_t)t*1536 + tid*8;
  f32x4 a = *(const f32x4*)xr;
  f32x4 b = *(const f32x4*)(xr+4);
  float ss = a[0]*a[0]+a[1]*a[1]+a[2]*a[2]+a[3]*a[3]
           + b[0]*b[0]+b[1]*b[1]+b[2]*b[2]+b[3]*b[3];
  #pragma unroll
  for (int m=1;m<64;m<<=1) ss += __shfl_xor(ss,m);
  __shared__ float red[3];
  if ((tid&63)==0) red[tid>>6]=ss;
  __syncthreads();
  float inv = rsqrtf((red[0]+red[1]+red[2])*(1.0f/1536.0f)+1e-6f);
  const float* wp = w + tid*8;
  f32x4 wa = *(const f32x4*)wp;
  f32x4 wb = *(const f32x4*)(wp+4);
  u16* op = o + (size_t)t*1536 + tid*8;
  #pragma unroll
  for (int j=0;j<4;++j) op[j]   = f2bf(a[j]*inv*wa[j]);
  #pragma unroll
  for (int j=0;j<4;++j) op[j+4] = f2bf(b[j]*inv*wb[j]);
}

//------------------------------------------------------------------
// m97-style 128x128 GEMM: A bf16 [M][K] (optionally row-gathered),
// Bt bf16 [N][K]. global_load_lds(16B) staging, linear LDS, BK=32,
// 4 waves (2x2 of 64x64), mfma 16x16x32 bf16.
// MODE 0: Cb = bf16(acc)
// MODE 1: Cf[idx] = resid[idx] + acc*0.22
// MODE 2: dual-N: silu(acc_g)*acc_u -> bf16 Cb  (Bt rows col0 and col0+halfN)
// MODE 4: atomicAdd(Cf[toks[row]], acc*gates[row])   (gates pre-scaled)
template<int MODE, int GATHER>
__global__ __launch_bounds__(256, (MODE==2)?2:3) void k_gemm(
    const u16* __restrict__ A, int lda,
    const u16* __restrict__ Bt, long strideB, int K,
    int Mfix, const int* __restrict__ cnts, const int* __restrict__ offs,
    const int* __restrict__ toks, const float* __restrict__ gates,
    int halfN,
    u16* __restrict__ Cb, int ldcb,
    float* __restrict__ Cf, int ldcf,
    const float* __restrict__ resid)
{
  int e = blockIdx.z;
  int M = cnts ? cnts[e] : Mfix;
  int m0 = blockIdx.y*128;
  if (m0 >= M) return;
  int roff = offs ? offs[e] : 0;
  const u16* Bp = Bt + (long)e*strideB;
  int col0 = blockIdx.x*128;

  __shared__ u16 Ash[4096];
  __shared__ u16 Bsh[4096];
  __shared__ u16 Bsh2[4096];

  int tid = threadIdx.x, wv = tid>>6, lane = tid&63;
  int lr = lane&15, lg = lane>>4;
  int wr = (wv>>1)*64, wc = (wv&1)*64;

  // hoisted staging addresses: thread tid covers (row=tid/4, kc=(tid&3)*8), rows +0 / +64
  int row0 = tid>>2, kc = (tid&3)*8;
  int gr0 = min(m0 + row0,      M-1);
  int gr1 = min(m0 + row0 + 64, M-1);
  int ar0, ar1;
  if (GATHER){ ar0 = toks[roff + gr0]; ar1 = toks[roff + gr1]; }
  else       { ar0 = roff + gr0;       ar1 = roff + gr1; }
  const u16* ap0 = A + (long)ar0*lda + kc;
  const u16* ap1 = A + (long)ar1*lda + kc;
  const u16* bp0 = Bp + (long)(col0 + row0)*K + kc;
  const u16* bp1 = bp0 + (long)64*K;
  const u16* c2p0 = bp0 + (long)halfN*K;
  const u16* c2p1 = bp1 + (long)halfN*K;

  u16* As0 = &Ash[wv*512];  u16* As1 = &Ash[2048 + wv*512];
  u16* Bs0 = &Bsh[wv*512];  u16* Bs1 = &Bsh[2048 + wv*512];
  u16* Cs0 = &Bsh2[wv*512]; u16* Cs1 = &Bsh2[2048 + wv*512];

  f32x4 acc[4][4];
  f32x4 acc2[4][4];
  #pragma unroll
  for (int m=0;m<4;++m)
    #pragma unroll
    for (int n=0;n<4;++n){
      acc[m][n] = (f32x4){0.f,0.f,0.f,0.f};
      if constexpr(MODE==2) acc2[m][n] = (f32x4){0.f,0.f,0.f,0.f};
    }

  int nk = K>>5;
  for (int kt=0; kt<nk; ++kt){
    __syncthreads();
    gload16(ap0, As0); gload16(ap1, As1);
    gload16(bp0, Bs0); gload16(bp1, Bs1);
    if constexpr(MODE==2){ gload16(c2p0, Cs0); gload16(c2p1, Cs1); }
    ap0 += 32; ap1 += 32; bp0 += 32; bp1 += 32;
    if constexpr(MODE==2){ c2p0 += 32; c2p1 += 32; }
    __syncthreads();

    short8 af[4], b1[4], b2f[4];
    #pragma unroll
    for (int m=0;m<4;++m) af[m] = *(const short8*)&Ash[(wr+m*16+lr)*32 + lg*8];
    #pragma unroll
    for (int n=0;n<4;++n) b1[n] = *(const short8*)&Bsh[(wc+n*16+lr)*32 + lg*8];
    if constexpr(MODE==2){
      #pragma unroll
      for (int n=0;n<4;++n) b2f[n] = *(const short8*)&Bsh2[(wc+n*16+lr)*32 + lg*8];
    }
    #pragma unroll
    for (int m=0;m<4;++m)
      #pragma unroll
      for (int n=0;n<4;++n){
        acc[m][n] = MFMA16(af[m], b1[n], acc[m][n]);
        if constexpr(MODE==2) acc2[m][n] = MFMA16(af[m], b2f[n], acc2[m][n]);
      }
  }

  #pragma unroll
  for (int m=0;m<4;++m)
    #pragma unroll
    for (int n=0;n<4;++n)
      #pragma unroll
      for (int rr=0;rr<4;++rr){
        int row = wr + m*16 + lg*4 + rr;   // C/D: col=lane&15, row=(lane>>4)*4+reg
        int gr = m0 + row;
        if (gr >= M) continue;
        int col = wc + n*16 + lr;
        float va = acc[m][n][rr];
        if constexpr(MODE==0){
          Cb[(long)(roff+gr)*ldcb + col0 + col] = f2bf(va);
        } else if constexpr(MODE==1){
          long idx = (long)gr*ldcf + col0 + col;
          Cf[idx] = resid[idx] + va*0.22f;
        } else if constexpr(MODE==2){
          float u = acc2[m][n][rr];
          float s = va/(1.f+__expf(-va))*u;
          Cb[(long)(roff+gr)*ldcb + col0 + col] = f2bf(s);
        } else {
          int tk = toks[roff+gr];
          float gt = gates[roff+gr];
          atomicAdd(&Cf[(long)tk*ldcf + col0 + col], va*gt);
        }
      }
}

//------------------------------------------------------------------
// RoPE in-place on q (T,24,64) and k (T,8,64), half=32, pairs (j, j+32)
__global__ __launch_bounds__(256) void k_rope(const int* __restrict__ pos,
    u16* __restrict__ qb, u16* __restrict__ kb)
{
  int gid = blockIdx.x*256 + threadIdx.x;   // T*1024
  int t = gid >> 10, p = gid & 1023;
  int j = p & 31;
  float invf = __expf(-(float)j * 0.28782313662425574f); // ln(10000)/32
  float ang = (float)pos[t] * invf;
  float sn, cs; __sincosf(ang, &sn, &cs);
  u16* base;
  if (p < 768) base = qb + (long)t*1536 + (p>>5)*64;
  else         base = kb + (long)t*512  + ((p-768)>>5)*64;
  float x1 = bf2f(base[j]), x2 = bf2f(base[j+32]);
  base[j]    = f2bf(x1*cs - x2*sn);
  base[j+32] = f2bf(x2*cs + x1*sn);
}

//------------------------------------------------------------------
// Causal flash attention, GQA 24q/8kv, hd=64. Block = 4 waves, 64 q rows.
__global__ __launch_bounds__(256,2) void k_attn(const u16* __restrict__ qg,
    const u16* __restrict__ kg, const u16* __restrict__ vg,
    u16* __restrict__ og)
{
  int qt = blockIdx.x, h = blockIdx.y, kvh = h/3;
  int tid = threadIdx.x, wv = tid>>6, lane = tid&63;
  int lr = lane&15, lg = lane>>4;
  __shared__ u16 Ksh[64*72];      // [krow][d], +8 pad
  __shared__ u16 Vsh[64*72];      // transposed: [d][krow]
  __shared__ u16 Psh[4][16*72];   // per-wave [qrow][krow]
  int q0 = qt*64;
  int qrow = q0 + wv*16 + lr;
  short8 qf[2];
  #pragma unroll
  for (int c=0;c<2;++c)
    qf[c] = *(const short8*)&qg[(long)qrow*1536 + h*64 + c*32 + lg*8];

  float m_[4], l_[4];
  f32x4 Ot[4];
  #pragma unroll
  for (int r=0;r<4;++r){ m_[r]=-1e30f; l_[r]=0.f; }
  #pragma unroll
  for (int d=0;d<4;++d) Ot[d]=(f32x4){0.f,0.f,0.f,0.f};

  for (int kt=0; kt<=qt; ++kt){
    __syncthreads();
    #pragma unroll
    for (int i=0;i<2;++i){
      int c = tid + i*256;
      int row = c>>3, dc = (c&7)*8;
      long gb = (long)(kt*64+row)*512 + kvh*64 + dc;
      short8 kv8 = *(const short8*)&kg[gb];
      *(short8*)&Ksh[row*72 + dc] = kv8;
      short8 vv = *(const short8*)&vg[gb];
      #pragma unroll
      for (int j=0;j<8;++j) Vsh[(dc+j)*72 + row] = (u16)vv[j];
    }
    __syncthreads();

    f32x4 S[4];
    #pragma unroll
    for (int n=0;n<4;++n) S[n]=(f32x4){0.f,0.f,0.f,0.f};
    #pragma unroll
    for (int n=0;n<4;++n)
      #pragma unroll
      for (int c=0;c<2;++c){
        short8 kf = *(const short8*)&Ksh[(n*16+lr)*72 + c*32 + lg*8];
        S[n] = MFMA16(qf[c], kf, S[n]);
      }

    float rmax[4] = {-1e30f,-1e30f,-1e30f,-1e30f};
    bool diag = (kt==qt);
    #pragma unroll
    for (int n=0;n<4;++n)
      #pragma unroll
      for (int r=0;r<4;++r){
        float sv = S[n][r]*0.015625f;
        if (diag){
          int colg = kt*64 + n*16 + lr;
          int rowg = q0 + wv*16 + lg*4 + r;
          if (colg > rowg) sv = -1e30f;
        }
        S[n][r] = sv;
        rmax[r] = fmaxf(rmax[r], sv);
      }
    #pragma unroll
    for (int msk=1; msk<16; msk<<=1){
      #pragma unroll
      for (int r=0;r<4;++r) rmax[r] = fmaxf(rmax[r], __shfl_xor(rmax[r], msk));
    }
    float alpha[4], rsum[4]={0.f,0.f,0.f,0.f};
    #pragma unroll
    for (int r=0;r<4;++r){
      float mn = fmaxf(m_[r], rmax[r]);
      alpha[r] = __expf(m_[r]-mn);
      m_[r] = mn;
    }
    #pragma unroll
    for (int n=0;n<4;++n)
      #pragma unroll
      for (int r=0;r<4;++r){
        float pv = __expf(S[n][r]-m_[r]);
        S[n][r]=pv; rsum[r]+=pv;
      }
    #pragma unroll
    for (int msk=1; msk<16; msk<<=1){
      #pragma unroll
      for (int r=0;r<4;++r) rsum[r] += __shfl_xor(rsum[r], msk);
    }
    #pragma unroll
    for (int r=0;r<4;++r) l_[r] = l_[r]*alpha[r] + rsum[r];
    #pragma unroll
    for (int d=0;d<4;++d)
      #pragma unroll
      for (int r=0;r<4;++r) Ot[d][r] *= alpha[r];

    #pragma unroll
    for (int n=0;n<4;++n)
      #pragma unroll
      for (int r=0;r<4;++r)
        Psh[wv][(lg*4+r)*72 + n*16 + lr] = f2bf(S[n][r]);
    __syncthreads();

    #pragma unroll
    for (int c=0;c<2;++c){
      short8 pf = *(const short8*)&Psh[wv][lr*72 + c*32 + lg*8];
      #pragma unroll
      for (int d=0;d<4;++d){
        short8 vf = *(const short8*)&Vsh[(d*16+lr)*72 + c*32 + lg*8];
        Ot[d] = MFMA16(pf, vf, Ot[d]);
      }
    }
  }

  #pragma unroll
  for (int d=0;d<4;++d)
    #pragma unroll
    for (int r=0;r<4;++r){
      int t = q0 + wv*16 + lg*4 + r;
      og[(long)t*1536 + h*64 + d*16 + lr] = f2bf(Ot[d][r]/l_[r]);
    }
}

//------------------------------------------------------------------
// Router: logits = h2 @ rw (1536x32), serial top-8 + softmax on lane 0
__global__ __launch_bounds__(64) void k_router(const u16* __restrict__ h2,
    const float* __restrict__ rw, int* __restrict__ topi, float* __restrict__ gatev)
{
  int t = blockIdx.x, lane = threadIdx.x;
  int e = lane & 31, hf = lane >> 5;
  const u16* hr = h2 + (size_t)t*1536 + hf*768;
  const float* wp = rw + (long)hf*768*32 + e;
  float s = 0.f;
  for (int d=0; d<768; ++d)
    s += bf2f(hr[d]) * wp[(long)d*32];
  s += __shfl_xor(s, 32);
  __shared__ float lgt[32];
  if (lane < 32) lgt[e] = s;
  __syncthreads();
  if (lane==0){
    u32 msk=0; float tv[8]; int ti[8];
    for (int kk=0;kk<8;++kk){
      float best=-1e30f; int bi=0;
      for (int j2=0;j2<32;++j2)
        if (!((msk>>j2)&1u) && lgt[j2] > best){ best=lgt[j2]; bi=j2; }
      msk |= 1u<<bi; tv[kk]=best; ti[kk]=bi;
    }
    float mx = tv[0], ssum = 0.f, ge[8];
    for (int kk=0;kk<8;++kk){ ge[kk]=__expf(tv[kk]-mx); ssum+=ge[kk]; }
    float isum = 1.f/ssum;
    for (int kk=0;kk<8;++kk){ topi[t*8+kk]=ti[kk]; gatev[t*8+kk]=ge[kk]*isum; }
  }
}

__global__ void k_hist(const int* __restrict__ topi, int* __restrict__ cnt){
  int i = blockIdx.x*256 + threadIdx.x;
  if (i < 4096*8) atomicAdd(&cnt[topi[i]], 1);
}
__global__ void k_scan(const int* __restrict__ cnt, int* __restrict__ offs, int* __restrict__ cur){
  if (threadIdx.x==0 && blockIdx.x==0){
    int a=0;
    for (int e2=0;e2<32;++e2){ offs[e2]=a; cur[e2]=a; a+=cnt[e2]; }
  }
}
__global__ void k_scatter(const int* __restrict__ topi, const float* __restrict__ gatev,
    int* __restrict__ cur, int* __restrict__ toks, float* __restrict__ gts){
  int i = blockIdx.x*256 + threadIdx.x;
  if (i < 4096*8){
    int e2 = topi[i];
    int p = atomicAdd(&cur[e2], 1);
    toks[p] = i>>3;
    gts[p] = gatev[i]*0.22f;   // fold RMULT into the gate
  }
}

//------------------------------------------------------------------
extern "C" void kernel_launch(void* const* d_in, const int* in_sizes, int n_in,
                              void* d_out, int out_size, void* d_ws, size_t ws_size,
                              hipStream_t stream)
{
  const int*   positions = (const int*)  d_in[0];
  const float* hs   = (const float*)d_in[1];
  const float* ln1w = (const float*)d_in[2];
  const float* wq   = (const float*)d_in[3];
  const float* wk   = (const float*)d_in[4];
  const float* wv   = (const float*)d_in[5];
  const float* wo   = (const float*)d_in[6];
  const float* ln2w = (const float*)d_in[7];
  const float* rww  = (const float*)d_in[8];
  const float* wgu  = (const float*)d_in[9];
  const float* wdn  = (const float*)d_in[10];
  const float* sgu  = (const float*)d_in[11];
  const float* sdn  = (const float*)d_in[12];
  float* out = (float*)d_out;

  char* ws = (char*)d_ws;
  size_t off = 0;
  auto alloc = [&](size_t b)->void*{ void* p = ws + off; off += (b + 255) & ~(size_t)255; return p; };

  u16* hbf     = (u16*)alloc((size_t)4096*1536*2);   // ln1 out; later reused as h2 (ln2 out)
  u16* qkv     = (u16*)alloc((size_t)33554432);      // q|k|v|attn-out; later reused as moe act
  u16* qbf  = qkv;
  u16* kbf  = qkv + (size_t)4096*1536;
  u16* vbf  = kbf + (size_t)4096*512;
  u16* aout = vbf + (size_t)4096*512;
  u16* act_moe = qkv;                                // 32768 x 512 bf16 overlays q/k/v/attn
  u16* act_sh  = (u16*)alloc((size_t)4096*1024*2);
  int*   topi  = (int*)  alloc(4096*8*4);
  float* gatev = (float*)alloc(4096*8*4);
  int*   toks  = (int*)  alloc(4096*8*4);
  float* gts   = (float*)alloc(4096*8*4);
  int*   cnt   = (int*)  alloc(512);
  int*   offs  = (int*)  alloc(512);
  int*   cur   = (int*)  alloc(512);
  // bf16-transposed weights [N][K]
  u16* wqT  = (u16*)alloc((size_t)1536*1536*2);
  u16* wkT  = (u16*)alloc((size_t)512*1536*2);
  u16* wvT  = (u16*)alloc((size_t)512*1536*2);
  u16* woT  = (u16*)alloc((size_t)1536*1536*2);
  u16* sguT = (u16*)alloc((size_t)2048*1536*2);
  u16* sdnT = (u16*)alloc((size_t)1536*1024*2);
  u16* wguT = (u16*)alloc((size_t)32*1024*1536*2);
  u16* wdnT = (u16*)alloc((size_t)32*1536*512*2);
  float* hidden2 = out;      // residual after attention lives in d_out
  u16*   h2bf = hbf;

  // 0. weight convert+transpose pre-pass (bf16, [N][K])
  k_wt<<<dim3(48,48,1), 256,0,stream>>>(wq,  wqT,  1536,1536, 0,0);
  k_wt<<<dim3(16,48,1), 256,0,stream>>>(wk,  wkT,  1536,512,  0,0);
  k_wt<<<dim3(16,48,1), 256,0,stream>>>(wv,  wvT,  1536,512,  0,0);
  k_wt<<<dim3(48,48,1), 256,0,stream>>>(wo,  woT,  1536,1536, 0,0);
  k_wt<<<dim3(64,48,1), 256,0,stream>>>(sgu, sguT, 1536,2048, 0,0);
  k_wt<<<dim3(48,32,1), 256,0,stream>>>(sdn, sdnT, 1024,1536, 0,0);
  k_wt<<<dim3(32,48,32),256,0,stream>>>(wgu, wguT, 1536,1024, (long)1536*1024, (long)1536*1024);
  k_wt<<<dim3(48,16,32),256,0,stream>>>(wdn, wdnT, 512,1536,  (long)512*1536,  (long)512*1536);

  // 1. ln1
  k_rmsnorm<<<4096,192,0,stream>>>(hs, ln1w, hbf);
  // 2-4. q/k/v projections
  k_gemm<0,0><<<dim3(12,32,1),256,0,stream>>>(hbf,1536, wqT,0,1536, 4096,nullptr,nullptr,nullptr,nullptr,0, qbf,1536, nullptr,0, nullptr);
  k_gemm<0,0><<<dim3(4,32,1), 256,0,stream>>>(hbf,1536, wkT,0,1536, 4096,nullptr,nullptr,nullptr,nullptr,0, kbf,512,  nullptr,0, nullptr);
  k_gemm<0,0><<<dim3(4,32,1), 256,0,stream>>>(hbf,1536, wvT,0,1536, 4096,nullptr,nullptr,nullptr,nullptr,0, vbf,512,  nullptr,0, nullptr);
  // 5. rope (q,k in place)
  k_rope<<<16384,256,0,stream>>>(positions, qbf, kbf);
  // 6. causal GQA flash attention
  k_attn<<<dim3(64,24,1),256,0,stream>>>(qbf, kbf, vbf, aout);
  // 7. o-proj + residual -> hidden2 (in d_out)
  k_gemm<1,0><<<dim3(12,32,1),256,0,stream>>>(aout,1536, woT,0,1536, 4096,nullptr,nullptr,nullptr,nullptr,0, nullptr,0, hidden2,1536, hs);
  // 8. ln2
  k_rmsnorm<<<4096,192,0,stream>>>(hidden2, ln2w, h2bf);
  // 9. router + top-8
  k_router<<<4096,64,0,stream>>>(h2bf, rww, topi, gatev);
  // 10-13. expert grouping
  hipMemsetAsync(cnt, 0, 32*4, stream);
  k_hist<<<128,256,0,stream>>>(topi, cnt);
  k_scan<<<1,64,0,stream>>>(cnt, offs, cur);
  k_scatter<<<128,256,0,stream>>>(topi, gatev, cur, toks, gts);
  // 14. moe gate_up + silu*mul (gathered rows)
  k_gemm<2,1><<<dim3(4,32,32),256,0,stream>>>(h2bf,1536, wguT,(long)1024*1536,1536, 0,cnt,offs,toks,nullptr, 512, act_moe,512, nullptr,0, nullptr);
  // 15. shared gate_up + silu*mul
  k_gemm<2,0><<<dim3(8,32,1),256,0,stream>>>(h2bf,1536, sguT,0,1536, 4096,nullptr,nullptr,nullptr,nullptr, 1024, act_sh,1024, nullptr,0, nullptr);
  // 16. shared down: out = hidden2 + shared*0.22 (in-place on d_out)
  k_gemm<1,0><<<dim3(12,32,1),256,0,stream>>>(act_sh,1024, sdnT,0,1024, 4096,nullptr,nullptr,nullptr,nullptr,0, nullptr,0, out,1536, out);
  // 17. moe down, (gate*0.22)-scaled atomic scatter-add into out
  k_gemm<4,0><<<dim3(12,32,32),256,0,stream>>>(act_moe,512, wdnT,(long)1536*512,512, 0,cnt,offs,toks,gts, 0, nullptr,0, out,1536, nullptr);

  (void)in_sizes; (void)n_in; (void)out_size; (void)ws_size;
}

// Round 3
// 1310.307 us; speedup vs baseline: 2.0437x; 1.0790x over previous
//
#include <hip/hip_runtime.h>
#include <stdint.h>

using u16 = unsigned short;
using u32 = unsigned int;

typedef __attribute__((ext_vector_type(8))) short short8;
typedef __attribute__((ext_vector_type(4))) short short4v;
typedef __attribute__((ext_vector_type(4))) float f32x4;

#define MFMA16(a,b,c) __builtin_amdgcn_mfma_f32_16x16x32_bf16(a,b,c,0,0,0)

__device__ __forceinline__ u16 f2bf(float f){
  u32 u = __float_as_uint(f);
  u += 0x7fffu + ((u>>16)&1u);
  return (u16)(u>>16);
}
__device__ __forceinline__ float bf2f(u16 b){ return __uint_as_float(((u32)b)<<16); }

__device__ __forceinline__ void gload16(const void* g, void* l){
  __builtin_amdgcn_global_load_lds(
      (const __attribute__((address_space(1))) u32*)g,
      (__attribute__((address_space(3))) u32*)l, 16, 0, 0);
}

//------------------------------------------------------------------
// Weight prep: src f32 [K][N] -> dst bf16 [N][K]  (per blockIdx.z matrix)
__global__ __launch_bounds__(256) void k_wt(const float* __restrict__ src,
    u16* __restrict__ dst, int K, int N, long sstride, long dstride)
{
  __shared__ float tile[32][33];
  int nb = blockIdx.x*32, kb = blockIdx.y*32;
  const float* S = src + (long)blockIdx.z*sstride;
  u16* D = dst + (long)blockIdx.z*dstride;
  int tid = threadIdx.x;
  int r = tid>>3, c4 = (tid&7)*4;
  f32x4 v = *(const f32x4*)&S[(long)(kb+r)*N + nb + c4];
  tile[r][c4+0]=v[0]; tile[r][c4+1]=v[1]; tile[r][c4+2]=v[2]; tile[r][c4+3]=v[3];
  __syncthreads();
  short4v o;
  o[0]=(short)f2bf(tile[c4+0][r]);
  o[1]=(short)f2bf(tile[c4+1][r]);
  o[2]=(short)f2bf(tile[c4+2][r]);
  o[3]=(short)f2bf(tile[c4+3][r]);
  *(short4v*)&D[(long)(nb+r)*K + kb + c4] = o;
}

//------------------------------------------------------------------
// V transpose: vbf [4096][8][64] bf16 -> vT [8][64][4096] bf16
// grid (64 t-tiles, 8 kvh), 256 thr
__global__ __launch_bounds__(256) void k_vt(const u16* __restrict__ v,
                                            u16* __restrict__ vT)
{
  __shared__ u16 t_[64*72];
  int t0 = blockIdx.x*64, kvh = blockIdx.y;
  int tid = threadIdx.x;
  #pragma unroll
  for (int i=0;i<2;++i){
    int c = tid + i*256;
    int row = c>>3, dc = (c&7)*8;
    *(short8*)&t_[row*72 + dc] = *(const short8*)&v[(long)(t0+row)*512 + kvh*64 + dc];
  }
  __syncthreads();
  #pragma unroll
  for (int i=0;i<2;++i){
    int c = tid + i*256;
    int d = c>>3, tc = (c&7)*8;
    short8 o;
    #pragma unroll
    for (int j=0;j<8;++j) o[j] = (short)t_[(tc+j)*72 + d];
    *(short8*)&vT[(long)(kvh*64 + d)*4096 + t0 + tc] = o;
  }
}

//------------------------------------------------------------------
// RMSNorm: f32 [T,1536] -> bf16 [T,1536]
__global__ __launch_bounds__(192) void k_rmsnorm(const float* __restrict__ x,
                                                 const float* __restrict__ w,
                                                 u16* __restrict__ o)
{
  int t = blockIdx.x, tid = threadIdx.x;
  const float* xr = x + (size_t)t*1536 + tid*8;
  f32x4 a = *(const f32x4*)xr;
  f32x4 b = *(const f32x4*)(xr+4);
  float ss = a[0]*a[0]+a[1]*a[1]+a[2]*a[2]+a[3]*a[3]
           + b[0]*b[0]+b[1]*b[1]+b[2]*b[2]+b[3]*b[3];
  #pragma unroll
  for (int m=1;m<64;m<<=1) ss += __shfl_xor(ss,m);
  __shared__ float red[3];
  if ((tid&63)==0) red[tid>>6]=ss;
  __syncthreads();
  float inv = rsqrtf((red[0]+red[1]+red[2])*(1.0f/1536.0f)+1e-6f);
  const float* wp = w + tid*8;
  f32x4 wa = *(const f32x4*)wp;
  f32x4 wb = *(const f32x4*)(wp+4);
  u16* op = o + (size_t)t*1536 + tid*8;
  #pragma unroll
  for (int j=0;j<4;++j) op[j]   = f2bf(a[j]*inv*wa[j]);
  #pragma unroll
  for (int j=0;j<4;++j) op[j+4] = f2bf(b[j]*inv*wb[j]);
}

//------------------------------------------------------------------
// m97-style 128x128 GEMM: A bf16 [M][K] (optionally row-gathered),
// Bt bf16 [N][K]. global_load_lds(16B) staging, linear LDS, BK=32,
// 4 waves (2x2 of 64x64), mfma 16x16x32 bf16.
template<int MODE, int GATHER>
__global__ __launch_bounds__(256, (MODE==2)?2:3) void k_gemm(
    const u16* __restrict__ A, int lda,
    const u16* __restrict__ Bt, long strideB, int K,
    int Mfix, const int* __restrict__ cnts, const int* __restrict__ offs,
    const int* __restrict__ toks, const float* __restrict__ gates,
    int halfN,
    u16* __restrict__ Cb, int ldcb,
    float* __restrict__ Cf, int ldcf,
    const float* __restrict__ resid)
{
  int e = blockIdx.z;
  int M = cnts ? cnts[e] : Mfix;
  int m0 = blockIdx.y*128;
  if (m0 >= M) return;
  int roff = offs ? offs[e] : 0;
  const u16* Bp = Bt + (long)e*strideB;
  int col0 = blockIdx.x*128;

  __shared__ u16 Ash[4096];
  __shared__ u16 Bsh[4096];
  __shared__ u16 Bsh2[4096];

  int tid = threadIdx.x, wv = tid>>6, lane = tid&63;
  int lr = lane&15, lg = lane>>4;
  int wr = (wv>>1)*64, wc = (wv&1)*64;

  int row0 = tid>>2, kc = (tid&3)*8;
  int gr0 = min(m0 + row0,      M-1);
  int gr1 = min(m0 + row0 + 64, M-1);
  int ar0, ar1;
  if (GATHER){ ar0 = toks[roff + gr0]; ar1 = toks[roff + gr1]; }
  else       { ar0 = roff + gr0;       ar1 = roff + gr1; }
  const u16* ap0 = A + (long)ar0*lda + kc;
  const u16* ap1 = A + (long)ar1*lda + kc;
  const u16* bp0 = Bp + (long)(col0 + row0)*K + kc;
  const u16* bp1 = bp0 + (long)64*K;
  const u16* c2p0 = bp0 + (long)halfN*K;
  const u16* c2p1 = bp1 + (long)halfN*K;

  u16* As0 = &Ash[wv*512];  u16* As1 = &Ash[2048 + wv*512];
  u16* Bs0 = &Bsh[wv*512];  u16* Bs1 = &Bsh[2048 + wv*512];
  u16* Cs0 = &Bsh2[wv*512]; u16* Cs1 = &Bsh2[2048 + wv*512];

  f32x4 acc[4][4];
  f32x4 acc2[4][4];
  #pragma unroll
  for (int m=0;m<4;++m)
    #pragma unroll
    for (int n=0;n<4;++n){
      acc[m][n] = (f32x4){0.f,0.f,0.f,0.f};
      if constexpr(MODE==2) acc2[m][n] = (f32x4){0.f,0.f,0.f,0.f};
    }

  int nk = K>>5;
  for (int kt=0; kt<nk; ++kt){
    __syncthreads();
    gload16(ap0, As0); gload16(ap1, As1);
    gload16(bp0, Bs0); gload16(bp1, Bs1);
    if constexpr(MODE==2){ gload16(c2p0, Cs0); gload16(c2p1, Cs1); }
    ap0 += 32; ap1 += 32; bp0 += 32; bp1 += 32;
    if constexpr(MODE==2){ c2p0 += 32; c2p1 += 32; }
    __syncthreads();

    short8 af[4], b1[4], b2f[4];
    #pragma unroll
    for (int m=0;m<4;++m) af[m] = *(const short8*)&Ash[(wr+m*16+lr)*32 + lg*8];
    #pragma unroll
    for (int n=0;n<4;++n) b1[n] = *(const short8*)&Bsh[(wc+n*16+lr)*32 + lg*8];
    if constexpr(MODE==2){
      #pragma unroll
      for (int n=0;n<4;++n) b2f[n] = *(const short8*)&Bsh2[(wc+n*16+lr)*32 + lg*8];
    }
    #pragma unroll
    for (int m=0;m<4;++m)
      #pragma unroll
      for (int n=0;n<4;++n){
        acc[m][n] = MFMA16(af[m], b1[n], acc[m][n]);
        if constexpr(MODE==2) acc2[m][n] = MFMA16(af[m], b2f[n], acc2[m][n]);
      }
  }

  #pragma unroll
  for (int m=0;m<4;++m)
    #pragma unroll
    for (int n=0;n<4;++n)
      #pragma unroll
      for (int rr=0;rr<4;++rr){
        int row = wr + m*16 + lg*4 + rr;
        int gr = m0 + row;
        if (gr >= M) continue;
        int col = wc + n*16 + lr;
        float va = acc[m][n][rr];
        if constexpr(MODE==0){
          Cb[(long)(roff+gr)*ldcb + col0 + col] = f2bf(va);
        } else if constexpr(MODE==1){
          long idx = (long)gr*ldcf + col0 + col;
          Cf[idx] = resid[idx] + va*0.22f;
        } else if constexpr(MODE==2){
          float u = acc2[m][n][rr];
          float s = va/(1.f+__expf(-va))*u;
          Cb[(long)(roff+gr)*ldcb + col0 + col] = f2bf(s);
        } else {
          int tk = toks[roff+gr];
          float gt = gates[roff+gr];
          atomicAdd(&Cf[(long)tk*ldcf + col0 + col], va*gt);
        }
      }
}

//------------------------------------------------------------------
// RoPE in-place on q (T,24,64) and k (T,8,64), half=32, pairs (j, j+32)
__global__ __launch_bounds__(256) void k_rope(const int* __restrict__ pos,
    u16* __restrict__ qb, u16* __restrict__ kb)
{
  int gid = blockIdx.x*256 + threadIdx.x;   // T*1024
  int t = gid >> 10, p = gid & 1023;
  int j = p & 31;
  float invf = __expf(-(float)j * 0.28782313662425574f); // ln(10000)/32
  float ang = (float)pos[t] * invf;
  float sn, cs; __sincosf(ang, &sn, &cs);
  u16* base;
  if (p < 768) base = qb + (long)t*1536 + (p>>5)*64;
  else         base = kb + (long)t*512  + ((p-768)>>5)*64;
  float x1 = bf2f(base[j]), x2 = bf2f(base[j+32]);
  base[j]    = f2bf(x1*cs - x2*sn);
  base[j+32] = f2bf(x2*cs + x1*sn);
}

//------------------------------------------------------------------
// Causal flash attention, GQA: one block per (kv-head, q-tile of 64),
// processes all 3 q-heads of the group. 4 waves x 16 q-rows.
// K staged [krow][d]; V staged from pre-transposed vT as [d][krow].
// Reg double-buffer on K/V; no barrier between P-store and PV (Psh wave-private).
__global__ __launch_bounds__(256,2) void k_attn(const u16* __restrict__ qg,
    const u16* __restrict__ kg, const u16* __restrict__ vT,
    u16* __restrict__ og)
{
  int bid = blockIdx.x;               // 512 = 64 qt x 8 kvh
  int kvh = bid & 7;
  int ii = bid >> 3;
  int qt = (ii < 32) ? (63 - ii) : (ii - 32);   // heavy-first for load balance
  int tid = threadIdx.x, wv = tid>>6, lane = tid&63;
  int lr = lane&15, lg = lane>>4;
  __shared__ u16 Ksh[64*72];      // [krow][d]
  __shared__ u16 Vsh[64*72];      // [d][krow]
  __shared__ u16 Psh[4][16*72];   // per-wave [qrow][krow]
  int q0 = qt*64;
  int qrow = q0 + wv*16 + lr;
  short8 qf[3][2];
  #pragma unroll
  for (int hh=0;hh<3;++hh)
    #pragma unroll
    for (int c=0;c<2;++c)
      qf[hh][c] = *(const short8*)&qg[(long)qrow*1536 + (kvh*3+hh)*64 + c*32 + lg*8];

  float m_[3][4], l_[3][4];
  f32x4 Ot[3][4];
  #pragma unroll
  for (int hh=0;hh<3;++hh)
    #pragma unroll
    for (int r=0;r<4;++r){ m_[hh][r]=-1e30f; l_[hh][r]=0.f; }
  #pragma unroll
  for (int hh=0;hh<3;++hh)
    #pragma unroll
    for (int d=0;d<4;++d) Ot[hh][d]=(f32x4){0.f,0.f,0.f,0.f};

  int srow = tid>>3, sdc = (tid&7)*8;       // staging coords (rows +0/+32)
  short8 kreg[2], vreg[2];
  auto loadKV = [&](int kt){
    #pragma unroll
    for (int i=0;i<2;++i){
      int row = srow + i*32;
      kreg[i] = *(const short8*)&kg[(long)(kt*64+row)*512 + kvh*64 + sdc];
      vreg[i] = *(const short8*)&vT[(long)(kvh*64 + row)*4096 + kt*64 + sdc];
    }
  };
  loadKV(0);

  for (int kt=0; kt<=qt; ++kt){
    __syncthreads();
    #pragma unroll
    for (int i=0;i<2;++i){
      int row = srow + i*32;
      *(short8*)&Ksh[row*72 + sdc] = kreg[i];
      *(short8*)&Vsh[row*72 + sdc] = vreg[i];
    }
    __syncthreads();
    if (kt < qt) loadKV(kt+1);
    bool diag = (kt==qt);

    #pragma unroll
    for (int hh=0;hh<3;++hh){
      f32x4 S[4];
      #pragma unroll
      for (int n=0;n<4;++n) S[n]=(f32x4){0.f,0.f,0.f,0.f};
      #pragma unroll
      for (int n=0;n<4;++n)
        #pragma unroll
        for (int c=0;c<2;++c){
          short8 kf = *(const short8*)&Ksh[(n*16+lr)*72 + c*32 + lg*8];
          S[n] = MFMA16(qf[hh][c], kf, S[n]);
        }

      float rmax[4] = {-1e30f,-1e30f,-1e30f,-1e30f};
      #pragma unroll
      for (int n=0;n<4;++n)
        #pragma unroll
        for (int r=0;r<4;++r){
          float sv = S[n][r]*0.015625f;
          if (diag){
            int colg = n*16 + lr;
            int rowg = wv*16 + lg*4 + r;
            if (colg > rowg) sv = -1e30f;
          }
          S[n][r] = sv;
          rmax[r] = fmaxf(rmax[r], sv);
        }
      #pragma unroll
      for (int msk=1; msk<16; msk<<=1){
        #pragma unroll
        for (int r=0;r<4;++r) rmax[r] = fmaxf(rmax[r], __shfl_xor(rmax[r], msk));
      }
      float alpha[4], rsum[4]={0.f,0.f,0.f,0.f};
      #pragma unroll
      for (int r=0;r<4;++r){
        float mn = fmaxf(m_[hh][r], rmax[r]);
        alpha[r] = __expf(m_[hh][r]-mn);
        m_[hh][r] = mn;
      }
      #pragma unroll
      for (int n=0;n<4;++n)
        #pragma unroll
        for (int r=0;r<4;++r){
          float pv = __expf(S[n][r]-m_[hh][r]);
          S[n][r]=pv; rsum[r]+=pv;
        }
      #pragma unroll
      for (int msk=1; msk<16; msk<<=1){
        #pragma unroll
        for (int r=0;r<4;++r) rsum[r] += __shfl_xor(rsum[r], msk);
      }
      #pragma unroll
      for (int r=0;r<4;++r) l_[hh][r] = l_[hh][r]*alpha[r] + rsum[r];
      #pragma unroll
      for (int d=0;d<4;++d)
        #pragma unroll
        for (int r=0;r<4;++r) Ot[hh][d][r] *= alpha[r];

      #pragma unroll
      for (int n=0;n<4;++n)
        #pragma unroll
        for (int r=0;r<4;++r)
          Psh[wv][(lg*4+r)*72 + n*16 + lr] = f2bf(S[n][r]);
      // Psh is wave-private: no barrier needed, compiler orders via lgkmcnt
      #pragma unroll
      for (int c=0;c<2;++c){
        short8 pf = *(const short8*)&Psh[wv][lr*72 + c*32 + lg*8];
        #pragma unroll
        for (int d=0;d<4;++d){
          short8 vf = *(const short8*)&Vsh[(d*16+lr)*72 + c*32 + lg*8];
          Ot[hh][d] = MFMA16(pf, vf, Ot[hh][d]);
        }
      }
    }
  }

  #pragma unroll
  for (int hh=0;hh<3;++hh)
    #pragma unroll
    for (int d=0;d<4;++d)
      #pragma unroll
      for (int r=0;r<4;++r){
        int t = q0 + wv*16 + lg*4 + r;
        og[(long)t*1536 + (kvh*3+hh)*64 + d*16 + lr] = f2bf(Ot[hh][d][r]/l_[hh][r]);
      }
}

//------------------------------------------------------------------
// Router: logits = h2 @ rw (1536x32), serial top-8 + softmax on lane 0
__global__ __launch_bounds__(64) void k_router(const u16* __restrict__ h2,
    const float* __restrict__ rw, int* __restrict__ topi, float* __restrict__ gatev)
{
  int t = blockIdx.x, lane = threadIdx.x;
  int e = lane & 31, hf = lane >> 5;
  const u16* hr = h2 + (size_t)t*1536 + hf*768;
  const float* wp = rw + (long)hf*768*32 + e;
  float s = 0.f;
  for (int d=0; d<768; ++d)
    s += bf2f(hr[d]) * wp[(long)d*32];
  s += __shfl_xor(s, 32);
  __shared__ float lgt[32];
  if (lane < 32) lgt[e] = s;
  __syncthreads();
  if (lane==0){
    u32 msk=0; float tv[8]; int ti[8];
    for (int kk=0;kk<8;++kk){
      float best=-1e30f; int bi=0;
      for (int j2=0;j2<32;++j2)
        if (!((msk>>j2)&1u) && lgt[j2] > best){ best=lgt[j2]; bi=j2; }
      msk |= 1u<<bi; tv[kk]=best; ti[kk]=bi;
    }
    float mx = tv[0], ssum = 0.f, ge[8];
    for (int kk=0;kk<8;++kk){ ge[kk]=__expf(tv[kk]-mx); ssum+=ge[kk]; }
    float isum = 1.f/ssum;
    for (int kk=0;kk<8;++kk){ topi[t*8+kk]=ti[kk]; gatev[t*8+kk]=ge[kk]*isum; }
  }
}

__global__ void k_hist(const int* __restrict__ topi, int* __restrict__ cnt){
  int i = blockIdx.x*256 + threadIdx.x;
  if (i < 4096*8) atomicAdd(&cnt[topi[i]], 1);
}
__global__ void k_scan(const int* __restrict__ cnt, int* __restrict__ offs, int* __restrict__ cur){
  if (threadIdx.x==0 && blockIdx.x==0){
    int a=0;
    for (int e2=0;e2<32;++e2){ offs[e2]=a; cur[e2]=a; a+=cnt[e2]; }
  }
}
__global__ void k_scatter(const int* __restrict__ topi, const float* __restrict__ gatev,
    int* __restrict__ cur, int* __restrict__ toks, float* __restrict__ gts){
  int i = blockIdx.x*256 + threadIdx.x;
  if (i < 4096*8){
    int e2 = topi[i];
    int p = atomicAdd(&cur[e2], 1);
    toks[p] = i>>3;
    gts[p] = gatev[i]*0.22f;   // fold RMULT into the gate
  }
}

//------------------------------------------------------------------
extern "C" void kernel_launch(void* const* d_in, const int* in_sizes, int n_in,
                              void* d_out, int out_size, void* d_ws, size_t ws_size,
                              hipStream_t stream)
{
  const int*   positions = (const int*)  d_in[0];
  const float* hs   = (const float*)d_in[1];
  const float* ln1w = (const float*)d_in[2];
  const float* wq   = (const float*)d_in[3];
  const float* wk   = (const float*)d_in[4];
  const float* wv   = (const float*)d_in[5];
  const float* wo   = (const float*)d_in[6];
  const float* ln2w = (const float*)d_in[7];
  const float* rww  = (const float*)d_in[8];
  const float* wgu  = (const float*)d_in[9];
  const float* wdn  = (const float*)d_in[10];
  const float* sgu  = (const float*)d_in[11];
  const float* sdn  = (const float*)d_in[12];
  float* out = (float*)d_out;

  char* ws = (char*)d_ws;
  size_t off = 0;
  auto alloc = [&](size_t b)->void*{ void* p = ws + off; off += (b + 255) & ~(size_t)255; return p; };

  u16* hbf     = (u16*)alloc((size_t)4096*1536*2);   // ln1 out; later reused as h2 (ln2 out)
  u16* qkv     = (u16*)alloc((size_t)33554432);      // q|k|v|attn-out; later reused as moe act
  u16* qbf  = qkv;
  u16* kbf  = qkv + (size_t)4096*1536;
  u16* vbf  = kbf + (size_t)4096*512;
  u16* aout = vbf + (size_t)4096*512;
  u16* act_moe = qkv;                                // 32768 x 512 bf16 overlays q/k/v/attn
  u16* act_sh  = (u16*)alloc((size_t)4096*1024*2);
  u16* vT      = (u16*)alloc((size_t)8*64*4096*2);   // transposed V [kvh][d][t]
  int*   topi  = (int*)  alloc(4096*8*4);
  float* gatev = (float*)alloc(4096*8*4);
  int*   toks  = (int*)  alloc(4096*8*4);
  float* gts   = (float*)alloc(4096*8*4);
  int*   cnt   = (int*)  alloc(512);
  int*   offs  = (int*)  alloc(512);
  int*   cur   = (int*)  alloc(512);
  // bf16-transposed weights [N][K]
  u16* wqT  = (u16*)alloc((size_t)1536*1536*2);
  u16* wkT  = (u16*)alloc((size_t)512*1536*2);
  u16* wvT  = (u16*)alloc((size_t)512*1536*2);
  u16* woT  = (u16*)alloc((size_t)1536*1536*2);
  u16* sguT = (u16*)alloc((size_t)2048*1536*2);
  u16* sdnT = (u16*)alloc((size_t)1536*1024*2);
  u16* wguT = (u16*)alloc((size_t)32*1024*1536*2);
  u16* wdnT = (u16*)alloc((size_t)32*1536*512*2);
  float* hidden2 = out;      // residual after attention lives in d_out
  u16*   h2bf = hbf;

  // 0. weight convert+transpose pre-pass (bf16, [N][K])
  k_wt<<<dim3(48,48,1), 256,0,stream>>>(wq,  wqT,  1536,1536, 0,0);
  k_wt<<<dim3(16,48,1), 256,0,stream>>>(wk,  wkT,  1536,512,  0,0);
  k_wt<<<dim3(16,48,1), 256,0,stream>>>(wv,  wvT,  1536,512,  0,0);
  k_wt<<<dim3(48,48,1), 256,0,stream>>>(wo,  woT,  1536,1536, 0,0);
  k_wt<<<dim3(64,48,1), 256,0,stream>>>(sgu, sguT, 1536,2048, 0,0);
  k_wt<<<dim3(48,32,1), 256,0,stream>>>(sdn, sdnT, 1024,1536, 0,0);
  k_wt<<<dim3(32,48,32),256,0,stream>>>(wgu, wguT, 1536,1024, (long)1536*1024, (long)1536*1024);
  k_wt<<<dim3(48,16,32),256,0,stream>>>(wdn, wdnT, 512,1536,  (long)512*1536,  (long)512*1536);

  // 1. ln1
  k_rmsnorm<<<4096,192,0,stream>>>(hs, ln1w, hbf);
  // 2-4. q/k/v projections
  k_gemm<0,0><<<dim3(12,32,1),256,0,stream>>>(hbf,1536, wqT,0,1536, 4096,nullptr,nullptr,nullptr,nullptr,0, qbf,1536, nullptr,0, nullptr);
  k_gemm<0,0><<<dim3(4,32,1), 256,0,stream>>>(hbf,1536, wkT,0,1536, 4096,nullptr,nullptr,nullptr,nullptr,0, kbf,512,  nullptr,0, nullptr);
  k_gemm<0,0><<<dim3(4,32,1), 256,0,stream>>>(hbf,1536, wvT,0,1536, 4096,nullptr,nullptr,nullptr,nullptr,0, vbf,512,  nullptr,0, nullptr);
  // 5. rope (q,k in place), then V transpose
  k_rope<<<16384,256,0,stream>>>(positions, qbf, kbf);
  k_vt<<<dim3(64,8,1),256,0,stream>>>(vbf, vT);
  // 6. causal GQA flash attention (3 heads per block, balanced grid)
  k_attn<<<dim3(512,1,1),256,0,stream>>>(qbf, kbf, vT, aout);
  // 7. o-proj + residual -> hidden2 (in d_out)
  k_gemm<1,0><<<dim3(12,32,1),256,0,stream>>>(aout,1536, woT,0,1536, 4096,nullptr,nullptr,nullptr,nullptr,0, nullptr,0, hidden2,1536, hs);
  // 8. ln2
  k_rmsnorm<<<4096,192,0,stream>>>(hidden2, ln2w, h2bf);
  // 9. router + top-8
  k_router<<<4096,64,0,stream>>>(h2bf, rww, topi, gatev);
  // 10-13. expert grouping
  hipMemsetAsync(cnt, 0, 32*4, stream);
  k_hist<<<128,256,0,stream>>>(topi, cnt);
  k_scan<<<1,64,0,stream>>>(cnt, offs, cur);
  k_scatter<<<128,256,0,stream>>>(topi, gatev, cur, toks, gts);
  // 14. moe gate_up + silu*mul (gathered rows)
  k_gemm<2,1><<<dim3(4,32,32),256,0,stream>>>(h2bf,1536, wguT,(long)1024*1536,1536, 0,cnt,offs,toks,nullptr, 512, act_moe,512, nullptr,0, nullptr);
  // 15. shared gate_up + silu*mul
  k_gemm<2,0><<<dim3(8,32,1),256,0,stream>>>(h2bf,1536, sguT,0,1536, 4096,nullptr,nullptr,nullptr,nullptr, 1024, act_sh,1024, nullptr,0, nullptr);
  // 16. shared down: out = hidden2 + shared*0.22 (in-place on d_out)
  k_gemm<1,0><<<dim3(12,32,1),256,0,stream>>>(act_sh,1024, sdnT,0,1024, 4096,nullptr,nullptr,nullptr,nullptr,0, nullptr,0, out,1536, out);
  // 17. moe down, (gate*0.22)-scaled atomic scatter-add into out
  k_gemm<4,0><<<dim3(12,32,32),256,0,stream>>>(act_moe,512, wdnT,(long)1536*512,512, 0,cnt,offs,toks,gts, 0, nullptr,0, out,1536, nullptr);

  (void)in_sizes; (void)n_in; (void)out_size; (void)ws_size;
}

// Round 4
// 1199.520 us; speedup vs baseline: 2.2325x; 1.0924x over previous
//
#include <hip/hip_runtime.h>
#include <stdint.h>

using u16 = unsigned short;
using u32 = unsigned int;

typedef __attribute__((ext_vector_type(8))) short short8;
typedef __attribute__((ext_vector_type(4))) short short4v;
typedef __attribute__((ext_vector_type(4))) float f32x4;

#define MFMA16(a,b,c) __builtin_amdgcn_mfma_f32_16x16x32_bf16(a,b,c,0,0,0)

__device__ __forceinline__ u16 f2bf(float f){
  u32 u = __float_as_uint(f);
  u += 0x7fffu + ((u>>16)&1u);
  return (u16)(u>>16);
}
__device__ __forceinline__ float bf2f(u16 b){ return __uint_as_float(((u32)b)<<16); }

__device__ __forceinline__ void gload16(const void* g, void* l){
  __builtin_amdgcn_global_load_lds(
      (const __attribute__((address_space(1))) u32*)g,
      (__attribute__((address_space(3))) u32*)l, 16, 0, 0);
}

// 16-lane (DPP row) reductions — VALU only, no LDS traffic
__device__ __forceinline__ float red16_max(float x){
  float r;
  asm("v_max_f32 %0, %1, %1 row_ror:8 row_mask:0xf bank_mask:0xf" : "=v"(r) : "v"(x));
  asm("v_max_f32 %0, %1, %1 row_ror:4 row_mask:0xf bank_mask:0xf" : "=v"(r) : "v"(r));
  asm("v_max_f32 %0, %1, %1 row_ror:2 row_mask:0xf bank_mask:0xf" : "=v"(r) : "v"(r));
  asm("v_max_f32 %0, %1, %1 row_ror:1 row_mask:0xf bank_mask:0xf" : "=v"(r) : "v"(r));
  return r;
}
__device__ __forceinline__ float red16_sum(float x){
  float r;
  asm("v_add_f32 %0, %1, %1 row_ror:8 row_mask:0xf bank_mask:0xf" : "=v"(r) : "v"(x));
  asm("v_add_f32 %0, %1, %1 row_ror:4 row_mask:0xf bank_mask:0xf" : "=v"(r) : "v"(r));
  asm("v_add_f32 %0, %1, %1 row_ror:2 row_mask:0xf bank_mask:0xf" : "=v"(r) : "v"(r));
  asm("v_add_f32 %0, %1, %1 row_ror:1 row_mask:0xf bank_mask:0xf" : "=v"(r) : "v"(r));
  return r;
}

//------------------------------------------------------------------
// Weight prep: src f32 [K][N] -> dst bf16 [N][K]  (per blockIdx.z matrix)
__global__ __launch_bounds__(256) void k_wt(const float* __restrict__ src,
    u16* __restrict__ dst, int K, int N, long sstride, long dstride)
{
  __shared__ float tile[32][33];
  int nb = blockIdx.x*32, kb = blockIdx.y*32;
  const float* S = src + (long)blockIdx.z*sstride;
  u16* D = dst + (long)blockIdx.z*dstride;
  int tid = threadIdx.x;
  int r = tid>>3, c4 = (tid&7)*4;
  f32x4 v = *(const f32x4*)&S[(long)(kb+r)*N + nb + c4];
  tile[r][c4+0]=v[0]; tile[r][c4+1]=v[1]; tile[r][c4+2]=v[2]; tile[r][c4+3]=v[3];
  __syncthreads();
  short4v o;
  o[0]=(short)f2bf(tile[c4+0][r]);
  o[1]=(short)f2bf(tile[c4+1][r]);
  o[2]=(short)f2bf(tile[c4+2][r]);
  o[3]=(short)f2bf(tile[c4+3][r]);
  *(short4v*)&D[(long)(nb+r)*K + kb + c4] = o;
}

//------------------------------------------------------------------
// V transpose: vbf [4096][8][64] bf16 -> vT [8][64][4096] bf16
__global__ __launch_bounds__(256) void k_vt(const u16* __restrict__ v,
                                            u16* __restrict__ vT)
{
  __shared__ u16 t_[64*72];
  int t0 = blockIdx.x*64, kvh = blockIdx.y;
  int tid = threadIdx.x;
  #pragma unroll
  for (int i=0;i<2;++i){
    int c = tid + i*256;
    int row = c>>3, dc = (c&7)*8;
    *(short8*)&t_[row*72 + dc] = *(const short8*)&v[(long)(t0+row)*512 + kvh*64 + dc];
  }
  __syncthreads();
  #pragma unroll
  for (int i=0;i<2;++i){
    int c = tid + i*256;
    int d = c>>3, tc = (c&7)*8;
    short8 o;
    #pragma unroll
    for (int j=0;j<8;++j) o[j] = (short)t_[(tc+j)*72 + d];
    *(short8*)&vT[(long)(kvh*64 + d)*4096 + t0 + tc] = o;
  }
}

//------------------------------------------------------------------
// RMSNorm: f32 [T,1536] -> bf16 [T,1536]
__global__ __launch_bounds__(192) void k_rmsnorm(const float* __restrict__ x,
                                                 const float* __restrict__ w,
                                                 u16* __restrict__ o)
{
  int t = blockIdx.x, tid = threadIdx.x;
  const float* xr = x + (size_t)t*1536 + tid*8;
  f32x4 a = *(const f32x4*)xr;
  f32x4 b = *(const f32x4*)(xr+4);
  float ss = a[0]*a[0]+a[1]*a[1]+a[2]*a[2]+a[3]*a[3]
           + b[0]*b[0]+b[1]*b[1]+b[2]*b[2]+b[3]*b[3];
  #pragma unroll
  for (int m=1;m<64;m<<=1) ss += __shfl_xor(ss,m);
  __shared__ float red[3];
  if ((tid&63)==0) red[tid>>6]=ss;
  __syncthreads();
  float inv = rsqrtf((red[0]+red[1]+red[2])*(1.0f/1536.0f)+1e-6f);
  const float* wp = w + tid*8;
  f32x4 wa = *(const f32x4*)wp;
  f32x4 wb = *(const f32x4*)(wp+4);
  u16* op = o + (size_t)t*1536 + tid*8;
  #pragma unroll
  for (int j=0;j<4;++j) op[j]   = f2bf(a[j]*inv*wa[j]);
  #pragma unroll
  for (int j=0;j<4;++j) op[j+4] = f2bf(b[j]*inv*wb[j]);
}

//------------------------------------------------------------------
// m97-style 128x128 GEMM (unchanged from round 3)
template<int MODE, int GATHER>
__global__ __launch_bounds__(256, (MODE==2)?2:3) void k_gemm(
    const u16* __restrict__ A, int lda,
    const u16* __restrict__ Bt, long strideB, int K,
    int Mfix, const int* __restrict__ cnts, const int* __restrict__ offs,
    const int* __restrict__ toks, const float* __restrict__ gates,
    int halfN,
    u16* __restrict__ Cb, int ldcb,
    float* __restrict__ Cf, int ldcf,
    const float* __restrict__ resid)
{
  int e = blockIdx.z;
  int M = cnts ? cnts[e] : Mfix;
  int m0 = blockIdx.y*128;
  if (m0 >= M) return;
  int roff = offs ? offs[e] : 0;
  const u16* Bp = Bt + (long)e*strideB;
  int col0 = blockIdx.x*128;

  __shared__ u16 Ash[4096];
  __shared__ u16 Bsh[4096];
  __shared__ u16 Bsh2[4096];

  int tid = threadIdx.x, wv = tid>>6, lane = tid&63;
  int lr = lane&15, lg = lane>>4;
  int wr = (wv>>1)*64, wc = (wv&1)*64;

  int row0 = tid>>2, kc = (tid&3)*8;
  int gr0 = min(m0 + row0,      M-1);
  int gr1 = min(m0 + row0 + 64, M-1);
  int ar0, ar1;
  if (GATHER){ ar0 = toks[roff + gr0]; ar1 = toks[roff + gr1]; }
  else       { ar0 = roff + gr0;       ar1 = roff + gr1; }
  const u16* ap0 = A + (long)ar0*lda + kc;
  const u16* ap1 = A + (long)ar1*lda + kc;
  const u16* bp0 = Bp + (long)(col0 + row0)*K + kc;
  const u16* bp1 = bp0 + (long)64*K;
  const u16* c2p0 = bp0 + (long)halfN*K;
  const u16* c2p1 = bp1 + (long)halfN*K;

  u16* As0 = &Ash[wv*512];  u16* As1 = &Ash[2048 + wv*512];
  u16* Bs0 = &Bsh[wv*512];  u16* Bs1 = &Bsh[2048 + wv*512];
  u16* Cs0 = &Bsh2[wv*512]; u16* Cs1 = &Bsh2[2048 + wv*512];

  f32x4 acc[4][4];
  f32x4 acc2[4][4];
  #pragma unroll
  for (int m=0;m<4;++m)
    #pragma unroll
    for (int n=0;n<4;++n){
      acc[m][n] = (f32x4){0.f,0.f,0.f,0.f};
      if constexpr(MODE==2) acc2[m][n] = (f32x4){0.f,0.f,0.f,0.f};
    }

  int nk = K>>5;
  for (int kt=0; kt<nk; ++kt){
    __syncthreads();
    gload16(ap0, As0); gload16(ap1, As1);
    gload16(bp0, Bs0); gload16(bp1, Bs1);
    if constexpr(MODE==2){ gload16(c2p0, Cs0); gload16(c2p1, Cs1); }
    ap0 += 32; ap1 += 32; bp0 += 32; bp1 += 32;
    if constexpr(MODE==2){ c2p0 += 32; c2p1 += 32; }
    __syncthreads();

    short8 af[4], b1[4], b2f[4];
    #pragma unroll
    for (int m=0;m<4;++m) af[m] = *(const short8*)&Ash[(wr+m*16+lr)*32 + lg*8];
    #pragma unroll
    for (int n=0;n<4;++n) b1[n] = *(const short8*)&Bsh[(wc+n*16+lr)*32 + lg*8];
    if constexpr(MODE==2){
      #pragma unroll
      for (int n=0;n<4;++n) b2f[n] = *(const short8*)&Bsh2[(wc+n*16+lr)*32 + lg*8];
    }
    #pragma unroll
    for (int m=0;m<4;++m)
      #pragma unroll
      for (int n=0;n<4;++n){
        acc[m][n] = MFMA16(af[m], b1[n], acc[m][n]);
        if constexpr(MODE==2) acc2[m][n] = MFMA16(af[m], b2f[n], acc2[m][n]);
      }
  }

  #pragma unroll
  for (int m=0;m<4;++m)
    #pragma unroll
    for (int n=0;n<4;++n)
      #pragma unroll
      for (int rr=0;rr<4;++rr){
        int row = wr + m*16 + lg*4 + rr;
        int gr = m0 + row;
        if (gr >= M) continue;
        int col = wc + n*16 + lr;
        float va = acc[m][n][rr];
        if constexpr(MODE==0){
          Cb[(long)(roff+gr)*ldcb + col0 + col] = f2bf(va);
        } else if constexpr(MODE==1){
          long idx = (long)gr*ldcf + col0 + col;
          Cf[idx] = resid[idx] + va*0.22f;
        } else if constexpr(MODE==2){
          float u = acc2[m][n][rr];
          float s = va/(1.f+__expf(-va))*u;
          Cb[(long)(roff+gr)*ldcb + col0 + col] = f2bf(s);
        } else {
          int tk = toks[roff+gr];
          float gt = gates[roff+gr];
          atomicAdd(&Cf[(long)tk*ldcf + col0 + col], va*gt);
        }
      }
}

//------------------------------------------------------------------
// RoPE in-place on q (T,24,64) and k (T,8,64)
__global__ __launch_bounds__(256) void k_rope(const int* __restrict__ pos,
    u16* __restrict__ qb, u16* __restrict__ kb)
{
  int gid = blockIdx.x*256 + threadIdx.x;
  int t = gid >> 10, p = gid & 1023;
  int j = p & 31;
  float invf = __expf(-(float)j * 0.28782313662425574f);
  float ang = (float)pos[t] * invf;
  float sn, cs; __sincosf(ang, &sn, &cs);
  u16* base;
  if (p < 768) base = qb + (long)t*1536 + (p>>5)*64;
  else         base = kb + (long)t*512  + ((p-768)>>5)*64;
  float x1 = bf2f(base[j]), x2 = bf2f(base[j+32]);
  base[j]    = f2bf(x1*cs - x2*sn);
  base[j+32] = f2bf(x2*cs + x1*sn);
}

//------------------------------------------------------------------
// Causal flash attention with KV-split (flash-decoding).
// Block = (kvh, qt, chunk): qt<32 -> single chunk (direct write);
// qt>=32 -> chunk0 = kt 0..31, chunk1 = kt 32..qt, bf16 partials + (m,l).
// DPP row-reductions (no LDS shuffles). 3 q-heads per block.
__global__ __launch_bounds__(256,3) void k_attn(const u16* __restrict__ qg,
    const u16* __restrict__ kg, const u16* __restrict__ vT,
    u16* __restrict__ og, u16* __restrict__ Opart, float* __restrict__ mlb)
{
  int bid = blockIdx.x;               // 768 = 96 x 8
  int kvh = bid & 7;
  int ii = bid >> 3;
  int qt, kt0, kt1, chunk; bool single;
  if (ii < 32)      { qt = 32+ii;        chunk = 0; kt0 = 0;  kt1 = 32;   single = false; }
  else if (ii < 64) { qt = 63-(ii-32);   chunk = 1; kt0 = 32; kt1 = qt+1; single = false; }
  else              { qt = 31-(ii-64);   chunk = 0; kt0 = 0;  kt1 = qt+1; single = true;  }

  int tid = threadIdx.x, wv = tid>>6, lane = tid&63;
  int lr = lane&15, lg = lane>>4;
  __shared__ u16 Ksh[64*72];      // [krow][d]
  __shared__ u16 Vsh[64*72];      // [d][krow]
  __shared__ u16 Psh[4][16*72];   // per-wave [qrow][krow]
  int q0 = qt*64;
  int qrow = q0 + wv*16 + lr;
  short8 qf[3][2];
  #pragma unroll
  for (int hh=0;hh<3;++hh)
    #pragma unroll
    for (int c=0;c<2;++c)
      qf[hh][c] = *(const short8*)&qg[(long)qrow*1536 + (kvh*3+hh)*64 + c*32 + lg*8];

  float m_[3][4], l_[3][4];
  f32x4 Ot[3][4];
  #pragma unroll
  for (int hh=0;hh<3;++hh)
    #pragma unroll
    for (int r=0;r<4;++r){ m_[hh][r]=-1e30f; l_[hh][r]=0.f; }
  #pragma unroll
  for (int hh=0;hh<3;++hh)
    #pragma unroll
    for (int d=0;d<4;++d) Ot[hh][d]=(f32x4){0.f,0.f,0.f,0.f};

  int srow = tid>>3, sdc = (tid&7)*8;
  short8 kreg[2], vreg[2];
  auto loadKV = [&](int kt){
    #pragma unroll
    for (int i=0;i<2;++i){
      int row = srow + i*32;
      kreg[i] = *(const short8*)&kg[(long)(kt*64+row)*512 + kvh*64 + sdc];
      vreg[i] = *(const short8*)&vT[(long)(kvh*64 + row)*4096 + kt*64 + sdc];
    }
  };
  loadKV(kt0);

  for (int kt=kt0; kt<kt1; ++kt){
    __syncthreads();
    #pragma unroll
    for (int i=0;i<2;++i){
      int row = srow + i*32;
      *(short8*)&Ksh[row*72 + sdc] = kreg[i];
      *(short8*)&Vsh[row*72 + sdc] = vreg[i];
    }
    __syncthreads();
    if (kt < kt1-1) loadKV(kt+1);
    bool diag = (kt==qt);

    #pragma unroll
    for (int hh=0;hh<3;++hh){
      f32x4 S[4];
      #pragma unroll
      for (int n=0;n<4;++n) S[n]=(f32x4){0.f,0.f,0.f,0.f};
      #pragma unroll
      for (int n=0;n<4;++n)
        #pragma unroll
        for (int c=0;c<2;++c){
          short8 kf = *(const short8*)&Ksh[(n*16+lr)*72 + c*32 + lg*8];
          S[n] = MFMA16(qf[hh][c], kf, S[n]);
        }

      float rmax[4] = {-1e30f,-1e30f,-1e30f,-1e30f};
      #pragma unroll
      for (int n=0;n<4;++n)
        #pragma unroll
        for (int r=0;r<4;++r){
          float sv = S[n][r]*0.015625f;
          if (diag){
            int colg = n*16 + lr;
            int rowg = wv*16 + lg*4 + r;
            if (colg > rowg) sv = -1e30f;
          }
          S[n][r] = sv;
          rmax[r] = fmaxf(rmax[r], sv);
        }
      #pragma unroll
      for (int r=0;r<4;++r) rmax[r] = red16_max(rmax[r]);

      float alpha[4], rsum[4];
      #pragma unroll
      for (int r=0;r<4;++r){
        float mn = fmaxf(m_[hh][r], rmax[r]);
        alpha[r] = __expf(m_[hh][r]-mn);
        m_[hh][r] = mn;
        rsum[r] = 0.f;
      }
      #pragma unroll
      for (int n=0;n<4;++n)
        #pragma unroll
        for (int r=0;r<4;++r){
          float pv = __expf(S[n][r]-m_[hh][r]);
          S[n][r]=pv; rsum[r]+=pv;
        }
      #pragma unroll
      for (int r=0;r<4;++r) rsum[r] = red16_sum(rsum[r]);
      #pragma unroll
      for (int r=0;r<4;++r) l_[hh][r] = l_[hh][r]*alpha[r] + rsum[r];
      #pragma unroll
      for (int d=0;d<4;++d)
        #pragma unroll
        for (int r=0;r<4;++r) Ot[hh][d][r] *= alpha[r];

      #pragma unroll
      for (int n=0;n<4;++n)
        #pragma unroll
        for (int r=0;r<4;++r)
          Psh[wv][(lg*4+r)*72 + n*16 + lr] = f2bf(S[n][r]);
      // Psh wave-private: compiler orders via lgkmcnt, no barrier
      #pragma unroll
      for (int c=0;c<2;++c){
        short8 pf = *(const short8*)&Psh[wv][lr*72 + c*32 + lg*8];
        #pragma unroll
        for (int d=0;d<4;++d){
          short8 vf = *(const short8*)&Vsh[(d*16+lr)*72 + c*32 + lg*8];
          Ot[hh][d] = MFMA16(pf, vf, Ot[hh][d]);
        }
      }
    }
  }

  if (single){
    #pragma unroll
    for (int hh=0;hh<3;++hh)
      #pragma unroll
      for (int d=0;d<4;++d)
        #pragma unroll
        for (int r=0;r<4;++r){
          int t = q0 + wv*16 + lg*4 + r;
          og[(long)t*1536 + (kvh*3+hh)*64 + d*16 + lr] = f2bf(Ot[hh][d][r]/l_[hh][r]);
        }
  } else {
    #pragma unroll
    for (int hh=0;hh<3;++hh){
      int h = kvh*3+hh;
      #pragma unroll
      for (int r=0;r<4;++r){
        int t = q0 + wv*16 + lg*4 + r;          // >= 2048 here
        long slot = ((long)(t-2048)*24 + h)*2 + chunk;
        #pragma unroll
        for (int d=0;d<4;++d)
          Opart[slot*64 + d*16 + lr] = f2bf(Ot[hh][d][r]);
        if (lr==0){ mlb[slot*2] = m_[hh][r]; mlb[slot*2+1] = l_[hh][r]; }
      }
    }
  }
}

//------------------------------------------------------------------
// Combine the two KV-split partials for t>=2048
__global__ __launch_bounds__(256) void k_comb(const u16* __restrict__ Opart,
    const float* __restrict__ mlb, u16* __restrict__ og)
{
  int gid = blockIdx.x*256 + threadIdx.x;   // 2048*24*64
  int d = gid & 63;
  long rowi = gid >> 6;                      // t'*24 + h
  long s0 = rowi*2, s1 = s0+1;
  float m0 = mlb[s0*2], l0 = mlb[s0*2+1];
  float m1 = mlb[s1*2], l1 = mlb[s1*2+1];
  float M = fmaxf(m0,m1);
  float w0 = __expf(m0-M), w1 = __expf(m1-M);
  float o = (bf2f(Opart[s0*64+d])*w0 + bf2f(Opart[s1*64+d])*w1) / (l0*w0 + l1*w1);
  int t = 2048 + (int)(rowi/24), h = (int)(rowi - (rowi/24)*24);
  og[(long)t*1536 + h*64 + d] = f2bf(o);
}

//------------------------------------------------------------------
// Router: logits = h2 @ rw (1536x32), serial top-8 + softmax on lane 0
__global__ __launch_bounds__(64) void k_router(const u16* __restrict__ h2,
    const float* __restrict__ rw, int* __restrict__ topi, float* __restrict__ gatev)
{
  int t = blockIdx.x, lane = threadIdx.x;
  int e = lane & 31, hf = lane >> 5;
  const u16* hr = h2 + (size_t)t*1536 + hf*768;
  const float* wp = rw + (long)hf*768*32 + e;
  float s = 0.f;
  for (int d=0; d<768; ++d)
    s += bf2f(hr[d]) * wp[(long)d*32];
  s += __shfl_xor(s, 32);
  __shared__ float lgt[32];
  if (lane < 32) lgt[e] = s;
  __syncthreads();
  if (lane==0){
    u32 msk=0; float tv[8]; int ti[8];
    for (int kk=0;kk<8;++kk){
      float best=-1e30f; int bi=0;
      for (int j2=0;j2<32;++j2)
        if (!((msk>>j2)&1u) && lgt[j2] > best){ best=lgt[j2]; bi=j2; }
      msk |= 1u<<bi; tv[kk]=best; ti[kk]=bi;
    }
    float mx = tv[0], ssum = 0.f, ge[8];
    for (int kk=0;kk<8;++kk){ ge[kk]=__expf(tv[kk]-mx); ssum+=ge[kk]; }
    float isum = 1.f/ssum;
    for (int kk=0;kk<8;++kk){ topi[t*8+kk]=ti[kk]; gatev[t*8+kk]=ge[kk]*isum; }
  }
}

__global__ void k_hist(const int* __restrict__ topi, int* __restrict__ cnt){
  int i = blockIdx.x*256 + threadIdx.x;
  if (i < 4096*8) atomicAdd(&cnt[topi[i]], 1);
}
__global__ void k_scan(const int* __restrict__ cnt, int* __restrict__ offs, int* __restrict__ cur){
  if (threadIdx.x==0 && blockIdx.x==0){
    int a=0;
    for (int e2=0;e2<32;++e2){ offs[e2]=a; cur[e2]=a; a+=cnt[e2]; }
  }
}
__global__ void k_scatter(const int* __restrict__ topi, const float* __restrict__ gatev,
    int* __restrict__ cur, int* __restrict__ toks, float* __restrict__ gts){
  int i = blockIdx.x*256 + threadIdx.x;
  if (i < 4096*8){
    int e2 = topi[i];
    int p = atomicAdd(&cur[e2], 1);
    toks[p] = i>>3;
    gts[p] = gatev[i]*0.22f;
  }
}

//------------------------------------------------------------------
extern "C" void kernel_launch(void* const* d_in, const int* in_sizes, int n_in,
                              void* d_out, int out_size, void* d_ws, size_t ws_size,
                              hipStream_t stream)
{
  const int*   positions = (const int*)  d_in[0];
  const float* hs   = (const float*)d_in[1];
  const float* ln1w = (const float*)d_in[2];
  const float* wq   = (const float*)d_in[3];
  const float* wk   = (const float*)d_in[4];
  const float* wv   = (const float*)d_in[5];
  const float* wo   = (const float*)d_in[6];
  const float* ln2w = (const float*)d_in[7];
  const float* rww  = (const float*)d_in[8];
  const float* wgu  = (const float*)d_in[9];
  const float* wdn  = (const float*)d_in[10];
  const float* sgu  = (const float*)d_in[11];
  const float* sdn  = (const float*)d_in[12];
  float* out = (float*)d_out;

  char* ws = (char*)d_ws;
  size_t off = 0;
  auto alloc = [&](size_t b)->void*{ void* p = ws + off; off += (b + 255) & ~(size_t)255; return p; };

  u16* hbf     = (u16*)alloc((size_t)4096*1536*2);   // ln1 out; attn partials; later h2
  u16* qkv     = (u16*)alloc((size_t)33554432);
  u16* qbf  = qkv;
  u16* kbf  = qkv + (size_t)4096*1536;
  u16* vbf  = kbf + (size_t)4096*512;
  u16* aout = vbf + (size_t)4096*512;
  u16* act_moe = qkv;
  u16* act_sh  = (u16*)alloc((size_t)4096*1024*2);   // also attn (m,l) buffer
  u16* vT      = (u16*)alloc((size_t)8*64*4096*2);
  int*   topi  = (int*)  alloc(4096*8*4);
  float* gatev = (float*)alloc(4096*8*4);
  int*   toks  = (int*)  alloc(4096*8*4);
  float* gts   = (float*)alloc(4096*8*4);
  int*   cnt   = (int*)  alloc(512);
  int*   offs  = (int*)  alloc(512);
  int*   cur   = (int*)  alloc(512);
  u16* wqT  = (u16*)alloc((size_t)1536*1536*2);
  u16* wkT  = (u16*)alloc((size_t)512*1536*2);
  u16* wvT  = (u16*)alloc((size_t)512*1536*2);
  u16* woT  = (u16*)alloc((size_t)1536*1536*2);
  u16* sguT = (u16*)alloc((size_t)2048*1536*2);
  u16* sdnT = (u16*)alloc((size_t)1536*1024*2);
  u16* wguT = (u16*)alloc((size_t)32*1024*1536*2);
  u16* wdnT = (u16*)alloc((size_t)32*1536*512*2);
  float* hidden2 = out;
  u16*   h2bf = hbf;
  u16*   Opart = hbf;            // dead between qkv-proj and ln2
  float* mlb   = (float*)act_sh; // dead until shared gate_up

  // 0. weight convert+transpose pre-pass (bf16, [N][K])
  k_wt<<<dim3(48,48,1), 256,0,stream>>>(wq,  wqT,  1536,1536, 0,0);
  k_wt<<<dim3(16,48,1), 256,0,stream>>>(wk,  wkT,  1536,512,  0,0);
  k_wt<<<dim3(16,48,1), 256,0,stream>>>(wv,  wvT,  1536,512,  0,0);
  k_wt<<<dim3(48,48,1), 256,0,stream>>>(wo,  woT,  1536,1536, 0,0);
  k_wt<<<dim3(64,48,1), 256,0,stream>>>(sgu, sguT, 1536,2048, 0,0);
  k_wt<<<dim3(48,32,1), 256,0,stream>>>(sdn, sdnT, 1024,1536, 0,0);
  k_wt<<<dim3(32,48,32),256,0,stream>>>(wgu, wguT, 1536,1024, (long)1536*1024, (long)1536*1024);
  k_wt<<<dim3(48,16,32),256,0,stream>>>(wdn, wdnT, 512,1536,  (long)512*1536,  (long)512*1536);

  // 1. ln1
  k_rmsnorm<<<4096,192,0,stream>>>(hs, ln1w, hbf);
  // 2-4. q/k/v projections
  k_gemm<0,0><<<dim3(12,32,1),256,0,stream>>>(hbf,1536, wqT,0,1536, 4096,nullptr,nullptr,nullptr,nullptr,0, qbf,1536, nullptr,0, nullptr);
  k_gemm<0,0><<<dim3(4,32,1), 256,0,stream>>>(hbf,1536, wkT,0,1536, 4096,nullptr,nullptr,nullptr,nullptr,0, kbf,512,  nullptr,0, nullptr);
  k_gemm<0,0><<<dim3(4,32,1), 256,0,stream>>>(hbf,1536, wvT,0,1536, 4096,nullptr,nullptr,nullptr,nullptr,0, vbf,512,  nullptr,0, nullptr);
  // 5. rope, V transpose
  k_rope<<<16384,256,0,stream>>>(positions, qbf, kbf);
  k_vt<<<dim3(64,8,1),256,0,stream>>>(vbf, vT);
  // 6. flash attention with KV-split, then combine
  k_attn<<<dim3(768,1,1),256,0,stream>>>(qbf, kbf, vT, aout, Opart, mlb);
  k_comb<<<12288,256,0,stream>>>(Opart, mlb, aout);
  // 7. o-proj + residual -> hidden2 (in d_out)
  k_gemm<1,0><<<dim3(12,32,1),256,0,stream>>>(aout,1536, woT,0,1536, 4096,nullptr,nullptr,nullptr,nullptr,0, nullptr,0, hidden2,1536, hs);
  // 8. ln2
  k_rmsnorm<<<4096,192,0,stream>>>(hidden2, ln2w, h2bf);
  // 9. router + top-8
  k_router<<<4096,64,0,stream>>>(h2bf, rww, topi, gatev);
  // 10-13. expert grouping
  hipMemsetAsync(cnt, 0, 32*4, stream);
  k_hist<<<128,256,0,stream>>>(topi, cnt);
  k_scan<<<1,64,0,stream>>>(cnt, offs, cur);
  k_scatter<<<128,256,0,stream>>>(topi, gatev, cur, toks, gts);
  // 14. moe gate_up + silu*mul (gathered rows)
  k_gemm<2,1><<<dim3(4,32,32),256,0,stream>>>(h2bf,1536, wguT,(long)1024*1536,1536, 0,cnt,offs,toks,nullptr, 512, act_moe,512, nullptr,0, nullptr);
  // 15. shared gate_up + silu*mul
  k_gemm<2,0><<<dim3(8,32,1),256,0,stream>>>(h2bf,1536, sguT,0,1536, 4096,nullptr,nullptr,nullptr,nullptr, 1024, act_sh,1024, nullptr,0, nullptr);
  // 16. shared down: out = hidden2 + shared*0.22
  k_gemm<1,0><<<dim3(12,32,1),256,0,stream>>>(act_sh,1024, sdnT,0,1024, 4096,nullptr,nullptr,nullptr,nullptr,0, nullptr,0, out,1536, out);
  // 17. moe down, (gate*0.22)-scaled atomic scatter-add into out
  k_gemm<4,0><<<dim3(12,32,32),256,0,stream>>>(act_moe,512, wdnT,(long)1536*512,512, 0,cnt,offs,toks,gts, 0, nullptr,0, out,1536, nullptr);

  (void)in_sizes; (void)n_in; (void)out_size; (void)ws_size;
}

// Round 5
// 1129.567 us; speedup vs baseline: 2.3708x; 1.0619x over previous
//
#include <hip/hip_runtime.h>
#include <stdint.h>

using u16 = unsigned short;
using u32 = unsigned int;

typedef __attribute__((ext_vector_type(8))) short short8;
typedef __attribute__((ext_vector_type(4))) short short4v;
typedef __attribute__((ext_vector_type(4))) float f32x4;

#define MFMA16(a,b,c) __builtin_amdgcn_mfma_f32_16x16x32_bf16(a,b,c,0,0,0)

__device__ __forceinline__ u16 f2bf(float f){
  u32 u = __float_as_uint(f);
  u += 0x7fffu + ((u>>16)&1u);
  return (u16)(u>>16);
}
__device__ __forceinline__ float bf2f(u16 b){ return __uint_as_float(((u32)b)<<16); }

__device__ __forceinline__ void gload16(const void* g, void* l){
  __builtin_amdgcn_global_load_lds(
      (const __attribute__((address_space(1))) u32*)g,
      (__attribute__((address_space(3))) u32*)l, 16, 0, 0);
}

// 16-lane (DPP row) reductions — VALU only, no LDS traffic
__device__ __forceinline__ float red16_max(float x){
  float r;
  asm("v_max_f32 %0, %1, %1 row_ror:8 row_mask:0xf bank_mask:0xf" : "=v"(r) : "v"(x));
  asm("v_max_f32 %0, %1, %1 row_ror:4 row_mask:0xf bank_mask:0xf" : "=v"(r) : "v"(r));
  asm("v_max_f32 %0, %1, %1 row_ror:2 row_mask:0xf bank_mask:0xf" : "=v"(r) : "v"(r));
  asm("v_max_f32 %0, %1, %1 row_ror:1 row_mask:0xf bank_mask:0xf" : "=v"(r) : "v"(r));
  return r;
}
__device__ __forceinline__ float red16_sum(float x){
  float r;
  asm("v_add_f32 %0, %1, %1 row_ror:8 row_mask:0xf bank_mask:0xf" : "=v"(r) : "v"(x));
  asm("v_add_f32 %0, %1, %1 row_ror:4 row_mask:0xf bank_mask:0xf" : "=v"(r) : "v"(r));
  asm("v_add_f32 %0, %1, %1 row_ror:2 row_mask:0xf bank_mask:0xf" : "=v"(r) : "v"(r));
  asm("v_add_f32 %0, %1, %1 row_ror:1 row_mask:0xf bank_mask:0xf" : "=v"(r) : "v"(r));
  return r;
}

//------------------------------------------------------------------
// Weight prep: src f32 [K][N] -> dst bf16 [N][K]  (per blockIdx.z matrix)
__global__ __launch_bounds__(256) void k_wt(const float* __restrict__ src,
    u16* __restrict__ dst, int K, int N, long sstride, long dstride)
{
  __shared__ float tile[32][33];
  int nb = blockIdx.x*32, kb = blockIdx.y*32;
  const float* S = src + (long)blockIdx.z*sstride;
  u16* D = dst + (long)blockIdx.z*dstride;
  int tid = threadIdx.x;
  int r = tid>>3, c4 = (tid&7)*4;
  f32x4 v = *(const f32x4*)&S[(long)(kb+r)*N + nb + c4];
  tile[r][c4+0]=v[0]; tile[r][c4+1]=v[1]; tile[r][c4+2]=v[2]; tile[r][c4+3]=v[3];
  __syncthreads();
  short4v o;
  o[0]=(short)f2bf(tile[c4+0][r]);
  o[1]=(short)f2bf(tile[c4+1][r]);
  o[2]=(short)f2bf(tile[c4+2][r]);
  o[3]=(short)f2bf(tile[c4+3][r]);
  *(short4v*)&D[(long)(nb+r)*K + kb + c4] = o;
}

//------------------------------------------------------------------
// V transpose: vbf [4096][8][64] bf16 -> vT [8][64][4096] bf16
__global__ __launch_bounds__(256) void k_vt(const u16* __restrict__ v,
                                            u16* __restrict__ vT)
{
  __shared__ u16 t_[64*72];
  int t0 = blockIdx.x*64, kvh = blockIdx.y;
  int tid = threadIdx.x;
  #pragma unroll
  for (int i=0;i<2;++i){
    int c = tid + i*256;
    int row = c>>3, dc = (c&7)*8;
    *(short8*)&t_[row*72 + dc] = *(const short8*)&v[(long)(t0+row)*512 + kvh*64 + dc];
  }
  __syncthreads();
  #pragma unroll
  for (int i=0;i<2;++i){
    int c = tid + i*256;
    int d = c>>3, tc = (c&7)*8;
    short8 o;
    #pragma unroll
    for (int j=0;j<8;++j) o[j] = (short)t_[(tc+j)*72 + d];
    *(short8*)&vT[(long)(kvh*64 + d)*4096 + t0 + tc] = o;
  }
}

//------------------------------------------------------------------
// RMSNorm: f32 [T,1536] -> bf16 [T,1536]
__global__ __launch_bounds__(192) void k_rmsnorm(const float* __restrict__ x,
                                                 const float* __restrict__ w,
                                                 u16* __restrict__ o)
{
  int t = blockIdx.x, tid = threadIdx.x;
  const float* xr = x + (size_t)t*1536 + tid*8;
  f32x4 a = *(const f32x4*)xr;
  f32x4 b = *(const f32x4*)(xr+4);
  float ss = a[0]*a[0]+a[1]*a[1]+a[2]*a[2]+a[3]*a[3]
           + b[0]*b[0]+b[1]*b[1]+b[2]*b[2]+b[3]*b[3];
  #pragma unroll
  for (int m=1;m<64;m<<=1) ss += __shfl_xor(ss,m);
  __shared__ float red[3];
  if ((tid&63)==0) red[tid>>6]=ss;
  __syncthreads();
  float inv = rsqrtf((red[0]+red[1]+red[2])*(1.0f/1536.0f)+1e-6f);
  const float* wp = w + tid*8;
  f32x4 wa = *(const f32x4*)wp;
  f32x4 wb = *(const f32x4*)(wp+4);
  u16* op = o + (size_t)t*1536 + tid*8;
  #pragma unroll
  for (int j=0;j<4;++j) op[j]   = f2bf(a[j]*inv*wa[j]);
  #pragma unroll
  for (int j=0;j<4;++j) op[j+4] = f2bf(b[j]*inv*wb[j]);
}

//------------------------------------------------------------------
// m97-style 128x128 GEMM.
// MODE 0: Cb = bf16(acc)
// MODE 1: Cf[idx] = resid[idx] + acc*0.22
// MODE 2: dual-N silu(g)*u -> bf16
// MODE 5: Cb[roff+gr] = bf16(acc * gates[roff+gr])   (sorted partial rows)
template<int MODE, int GATHER>
__global__ __launch_bounds__(256, (MODE==2)?2:3) void k_gemm(
    const u16* __restrict__ A, int lda,
    const u16* __restrict__ Bt, long strideB, int K,
    int Mfix, const int* __restrict__ cnts, const int* __restrict__ offs,
    const int* __restrict__ toks, const float* __restrict__ gates,
    int halfN,
    u16* __restrict__ Cb, int ldcb,
    float* __restrict__ Cf, int ldcf,
    const float* __restrict__ resid)
{
  int e = blockIdx.z;
  int M = cnts ? cnts[e] : Mfix;
  int m0 = blockIdx.y*128;
  if (m0 >= M) return;
  int roff = offs ? offs[e] : 0;
  const u16* Bp = Bt + (long)e*strideB;
  int col0 = blockIdx.x*128;

  __shared__ u16 Ash[4096];
  __shared__ u16 Bsh[4096];
  __shared__ u16 Bsh2[4096];

  int tid = threadIdx.x, wv = tid>>6, lane = tid&63;
  int lr = lane&15, lg = lane>>4;
  int wr = (wv>>1)*64, wc = (wv&1)*64;

  int row0 = tid>>2, kc = (tid&3)*8;
  int gr0 = min(m0 + row0,      M-1);
  int gr1 = min(m0 + row0 + 64, M-1);
  int ar0, ar1;
  if (GATHER){ ar0 = toks[roff + gr0]; ar1 = toks[roff + gr1]; }
  else       { ar0 = roff + gr0;       ar1 = roff + gr1; }
  const u16* ap0 = A + (long)ar0*lda + kc;
  const u16* ap1 = A + (long)ar1*lda + kc;
  const u16* bp0 = Bp + (long)(col0 + row0)*K + kc;
  const u16* bp1 = bp0 + (long)64*K;
  const u16* c2p0 = bp0 + (long)halfN*K;
  const u16* c2p1 = bp1 + (long)halfN*K;

  u16* As0 = &Ash[wv*512];  u16* As1 = &Ash[2048 + wv*512];
  u16* Bs0 = &Bsh[wv*512];  u16* Bs1 = &Bsh[2048 + wv*512];
  u16* Cs0 = &Bsh2[wv*512]; u16* Cs1 = &Bsh2[2048 + wv*512];

  f32x4 acc[4][4];
  f32x4 acc2[4][4];
  #pragma unroll
  for (int m=0;m<4;++m)
    #pragma unroll
    for (int n=0;n<4;++n){
      acc[m][n] = (f32x4){0.f,0.f,0.f,0.f};
      if constexpr(MODE==2) acc2[m][n] = (f32x4){0.f,0.f,0.f,0.f};
    }

  int nk = K>>5;
  for (int kt=0; kt<nk; ++kt){
    __syncthreads();
    gload16(ap0, As0); gload16(ap1, As1);
    gload16(bp0, Bs0); gload16(bp1, Bs1);
    if constexpr(MODE==2){ gload16(c2p0, Cs0); gload16(c2p1, Cs1); }
    ap0 += 32; ap1 += 32; bp0 += 32; bp1 += 32;
    if constexpr(MODE==2){ c2p0 += 32; c2p1 += 32; }
    __syncthreads();

    short8 af[4], b1[4], b2f[4];
    #pragma unroll
    for (int m=0;m<4;++m) af[m] = *(const short8*)&Ash[(wr+m*16+lr)*32 + lg*8];
    #pragma unroll
    for (int n=0;n<4;++n) b1[n] = *(const short8*)&Bsh[(wc+n*16+lr)*32 + lg*8];
    if constexpr(MODE==2){
      #pragma unroll
      for (int n=0;n<4;++n) b2f[n] = *(const short8*)&Bsh2[(wc+n*16+lr)*32 + lg*8];
    }
    #pragma unroll
    for (int m=0;m<4;++m)
      #pragma unroll
      for (int n=0;n<4;++n){
        acc[m][n] = MFMA16(af[m], b1[n], acc[m][n]);
        if constexpr(MODE==2) acc2[m][n] = MFMA16(af[m], b2f[n], acc2[m][n]);
      }
  }

  #pragma unroll
  for (int m=0;m<4;++m)
    #pragma unroll
    for (int n=0;n<4;++n)
      #pragma unroll
      for (int rr=0;rr<4;++rr){
        int row = wr + m*16 + lg*4 + rr;
        int gr = m0 + row;
        if (gr >= M) continue;
        int col = wc + n*16 + lr;
        float va = acc[m][n][rr];
        if constexpr(MODE==0){
          Cb[(long)(roff+gr)*ldcb + col0 + col] = f2bf(va);
        } else if constexpr(MODE==1){
          long idx = (long)gr*ldcf + col0 + col;
          Cf[idx] = resid[idx] + va*0.22f;
        } else if constexpr(MODE==2){
          float u = acc2[m][n][rr];
          float s = va/(1.f+__expf(-va))*u;
          Cb[(long)(roff+gr)*ldcb + col0 + col] = f2bf(s);
        } else if constexpr(MODE==5){
          float gt = gates[roff+gr];
          Cb[(long)(roff+gr)*ldcb + col0 + col] = f2bf(va*gt);
        }
      }
}

//------------------------------------------------------------------
// MoE sum: out[t] += sum_{kk} part[inv[t*8+kk]]  (partials pre-scaled)
__global__ __launch_bounds__(192) void k_moesum(const u16* __restrict__ part,
    const int* __restrict__ inv, float* __restrict__ out)
{
  int t = blockIdx.x, tid = threadIdx.x;
  int c = tid*8;
  float s[8] = {0.f,0.f,0.f,0.f,0.f,0.f,0.f,0.f};
  #pragma unroll
  for (int kk=0;kk<8;++kk){
    int slot = inv[t*8+kk];
    short8 v = *(const short8*)&part[(long)slot*1536 + c];
    #pragma unroll
    for (int j=0;j<8;++j) s[j] += bf2f((u16)v[j]);
  }
  float* op = out + (long)t*1536 + c;
  f32x4 o0 = *(const f32x4*)op;
  f32x4 o1 = *(const f32x4*)(op+4);
  #pragma unroll
  for (int j=0;j<4;++j){ o0[j] += s[j]; o1[j] += s[j+4]; }
  *(f32x4*)op = o0;
  *(f32x4*)(op+4) = o1;
}

//------------------------------------------------------------------
// RoPE in-place on q (T,24,64) and k (T,8,64)
__global__ __launch_bounds__(256) void k_rope(const int* __restrict__ pos,
    u16* __restrict__ qb, u16* __restrict__ kb)
{
  int gid = blockIdx.x*256 + threadIdx.x;
  int t = gid >> 10, p = gid & 1023;
  int j = p & 31;
  float invf = __expf(-(float)j * 0.28782313662425574f);
  float ang = (float)pos[t] * invf;
  float sn, cs; __sincosf(ang, &sn, &cs);
  u16* base;
  if (p < 768) base = qb + (long)t*1536 + (p>>5)*64;
  else         base = kb + (long)t*512  + ((p-768)>>5)*64;
  float x1 = bf2f(base[j]), x2 = bf2f(base[j+32]);
  base[j]    = f2bf(x1*cs - x2*sn);
  base[j+32] = f2bf(x2*cs + x1*sn);
}

//------------------------------------------------------------------
// Causal flash attention with KV-split (unchanged from round 4)
__global__ __launch_bounds__(256,3) void k_attn(const u16* __restrict__ qg,
    const u16* __restrict__ kg, const u16* __restrict__ vT,
    u16* __restrict__ og, u16* __restrict__ Opart, float* __restrict__ mlb)
{
  int bid = blockIdx.x;               // 768 = 96 x 8
  int kvh = bid & 7;
  int ii = bid >> 3;
  int qt, kt0, kt1, chunk; bool single;
  if (ii < 32)      { qt = 32+ii;        chunk = 0; kt0 = 0;  kt1 = 32;   single = false; }
  else if (ii < 64) { qt = 63-(ii-32);   chunk = 1; kt0 = 32; kt1 = qt+1; single = false; }
  else              { qt = 31-(ii-64);   chunk = 0; kt0 = 0;  kt1 = qt+1; single = true;  }

  int tid = threadIdx.x, wv = tid>>6, lane = tid&63;
  int lr = lane&15, lg = lane>>4;
  __shared__ u16 Ksh[64*72];
  __shared__ u16 Vsh[64*72];
  __shared__ u16 Psh[4][16*72];
  int q0 = qt*64;
  int qrow = q0 + wv*16 + lr;
  short8 qf[3][2];
  #pragma unroll
  for (int hh=0;hh<3;++hh)
    #pragma unroll
    for (int c=0;c<2;++c)
      qf[hh][c] = *(const short8*)&qg[(long)qrow*1536 + (kvh*3+hh)*64 + c*32 + lg*8];

  float m_[3][4], l_[3][4];
  f32x4 Ot[3][4];
  #pragma unroll
  for (int hh=0;hh<3;++hh)
    #pragma unroll
    for (int r=0;r<4;++r){ m_[hh][r]=-1e30f; l_[hh][r]=0.f; }
  #pragma unroll
  for (int hh=0;hh<3;++hh)
    #pragma unroll
    for (int d=0;d<4;++d) Ot[hh][d]=(f32x4){0.f,0.f,0.f,0.f};

  int srow = tid>>3, sdc = (tid&7)*8;
  short8 kreg[2], vreg[2];
  auto loadKV = [&](int kt){
    #pragma unroll
    for (int i=0;i<2;++i){
      int row = srow + i*32;
      kreg[i] = *(const short8*)&kg[(long)(kt*64+row)*512 + kvh*64 + sdc];
      vreg[i] = *(const short8*)&vT[(long)(kvh*64 + row)*4096 + kt*64 + sdc];
    }
  };
  loadKV(kt0);

  for (int kt=kt0; kt<kt1; ++kt){
    __syncthreads();
    #pragma unroll
    for (int i=0;i<2;++i){
      int row = srow + i*32;
      *(short8*)&Ksh[row*72 + sdc] = kreg[i];
      *(short8*)&Vsh[row*72 + sdc] = vreg[i];
    }
    __syncthreads();
    if (kt < kt1-1) loadKV(kt+1);
    bool diag = (kt==qt);

    #pragma unroll
    for (int hh=0;hh<3;++hh){
      f32x4 S[4];
      #pragma unroll
      for (int n=0;n<4;++n) S[n]=(f32x4){0.f,0.f,0.f,0.f};
      #pragma unroll
      for (int n=0;n<4;++n)
        #pragma unroll
        for (int c=0;c<2;++c){
          short8 kf = *(const short8*)&Ksh[(n*16+lr)*72 + c*32 + lg*8];
          S[n] = MFMA16(qf[hh][c], kf, S[n]);
        }

      float rmax[4] = {-1e30f,-1e30f,-1e30f,-1e30f};
      #pragma unroll
      for (int n=0;n<4;++n)
        #pragma unroll
        for (int r=0;r<4;++r){
          float sv = S[n][r]*0.015625f;
          if (diag){
            int colg = n*16 + lr;
            int rowg = wv*16 + lg*4 + r;
            if (colg > rowg) sv = -1e30f;
          }
          S[n][r] = sv;
          rmax[r] = fmaxf(rmax[r], sv);
        }
      #pragma unroll
      for (int r=0;r<4;++r) rmax[r] = red16_max(rmax[r]);

      float alpha[4], rsum[4];
      #pragma unroll
      for (int r=0;r<4;++r){
        float mn = fmaxf(m_[hh][r], rmax[r]);
        alpha[r] = __expf(m_[hh][r]-mn);
        m_[hh][r] = mn;
        rsum[r] = 0.f;
      }
      #pragma unroll
      for (int n=0;n<4;++n)
        #pragma unroll
        for (int r=0;r<4;++r){
          float pv = __expf(S[n][r]-m_[hh][r]);
          S[n][r]=pv; rsum[r]+=pv;
        }
      #pragma unroll
      for (int r=0;r<4;++r) rsum[r] = red16_sum(rsum[r]);
      #pragma unroll
      for (int r=0;r<4;++r) l_[hh][r] = l_[hh][r]*alpha[r] + rsum[r];
      #pragma unroll
      for (int d=0;d<4;++d)
        #pragma unroll
        for (int r=0;r<4;++r) Ot[hh][d][r] *= alpha[r];

      #pragma unroll
      for (int n=0;n<4;++n)
        #pragma unroll
        for (int r=0;r<4;++r)
          Psh[wv][(lg*4+r)*72 + n*16 + lr] = f2bf(S[n][r]);
      #pragma unroll
      for (int c=0;c<2;++c){
        short8 pf = *(const short8*)&Psh[wv][lr*72 + c*32 + lg*8];
        #pragma unroll
        for (int d=0;d<4;++d){
          short8 vf = *(const short8*)&Vsh[(d*16+lr)*72 + c*32 + lg*8];
          Ot[hh][d] = MFMA16(pf, vf, Ot[hh][d]);
        }
      }
    }
  }

  if (single){
    #pragma unroll
    for (int hh=0;hh<3;++hh)
      #pragma unroll
      for (int d=0;d<4;++d)
        #pragma unroll
        for (int r=0;r<4;++r){
          int t = q0 + wv*16 + lg*4 + r;
          og[(long)t*1536 + (kvh*3+hh)*64 + d*16 + lr] = f2bf(Ot[hh][d][r]/l_[hh][r]);
        }
  } else {
    #pragma unroll
    for (int hh=0;hh<3;++hh){
      int h = kvh*3+hh;
      #pragma unroll
      for (int r=0;r<4;++r){
        int t = q0 + wv*16 + lg*4 + r;
        long slot = ((long)(t-2048)*24 + h)*2 + chunk;
        #pragma unroll
        for (int d=0;d<4;++d)
          Opart[slot*64 + d*16 + lr] = f2bf(Ot[hh][d][r]);
        if (lr==0){ mlb[slot*2] = m_[hh][r]; mlb[slot*2+1] = l_[hh][r]; }
      }
    }
  }
}

//------------------------------------------------------------------
__global__ __launch_bounds__(256) void k_comb(const u16* __restrict__ Opart,
    const float* __restrict__ mlb, u16* __restrict__ og)
{
  int gid = blockIdx.x*256 + threadIdx.x;
  int d = gid & 63;
  long rowi = gid >> 6;
  long s0 = rowi*2, s1 = s0+1;
  float m0 = mlb[s0*2], l0 = mlb[s0*2+1];
  float m1 = mlb[s1*2], l1 = mlb[s1*2+1];
  float M = fmaxf(m0,m1);
  float w0 = __expf(m0-M), w1 = __expf(m1-M);
  float o = (bf2f(Opart[s0*64+d])*w0 + bf2f(Opart[s1*64+d])*w1) / (l0*w0 + l1*w1);
  int t = 2048 + (int)(rowi/24), h = (int)(rowi - (rowi/24)*24);
  og[(long)t*1536 + h*64 + d] = f2bf(o);
}

//------------------------------------------------------------------
__global__ __launch_bounds__(64) void k_router(const u16* __restrict__ h2,
    const float* __restrict__ rw, int* __restrict__ topi, float* __restrict__ gatev)
{
  int t = blockIdx.x, lane = threadIdx.x;
  int e = lane & 31, hf = lane >> 5;
  const u16* hr = h2 + (size_t)t*1536 + hf*768;
  const float* wp = rw + (long)hf*768*32 + e;
  float s = 0.f;
  for (int d=0; d<768; ++d)
    s += bf2f(hr[d]) * wp[(long)d*32];
  s += __shfl_xor(s, 32);
  __shared__ float lgt[32];
  if (lane < 32) lgt[e] = s;
  __syncthreads();
  if (lane==0){
    u32 msk=0; float tv[8]; int ti[8];
    for (int kk=0;kk<8;++kk){
      float best=-1e30f; int bi=0;
      for (int j2=0;j2<32;++j2)
        if (!((msk>>j2)&1u) && lgt[j2] > best){ best=lgt[j2]; bi=j2; }
      msk |= 1u<<bi; tv[kk]=best; ti[kk]=bi;
    }
    float mx = tv[0], ssum = 0.f, ge[8];
    for (int kk=0;kk<8;++kk){ ge[kk]=__expf(tv[kk]-mx); ssum+=ge[kk]; }
    float isum = 1.f/ssum;
    for (int kk=0;kk<8;++kk){ topi[t*8+kk]=ti[kk]; gatev[t*8+kk]=ge[kk]*isum; }
  }
}

__global__ void k_hist(const int* __restrict__ topi, int* __restrict__ cnt){
  int i = blockIdx.x*256 + threadIdx.x;
  if (i < 4096*8) atomicAdd(&cnt[topi[i]], 1);
}
__global__ void k_scan(const int* __restrict__ cnt, int* __restrict__ offs, int* __restrict__ cur){
  if (threadIdx.x==0 && blockIdx.x==0){
    int a=0;
    for (int e2=0;e2<32;++e2){ offs[e2]=a; cur[e2]=a; a+=cnt[e2]; }
  }
}
__global__ void k_scatter(const int* __restrict__ topi, const float* __restrict__ gatev,
    int* __restrict__ cur, int* __restrict__ toks, float* __restrict__ gts,
    int* __restrict__ inv){
  int i = blockIdx.x*256 + threadIdx.x;
  if (i < 4096*8){
    int e2 = topi[i];
    int p = atomicAdd(&cur[e2], 1);
    toks[p] = i>>3;
    gts[p] = gatev[i]*0.22f;
    inv[i] = p;
  }
}

//------------------------------------------------------------------
extern "C" void kernel_launch(void* const* d_in, const int* in_sizes, int n_in,
                              void* d_out, int out_size, void* d_ws, size_t ws_size,
                              hipStream_t stream)
{
  const int*   positions = (const int*)  d_in[0];
  const float* hs   = (const float*)d_in[1];
  const float* ln1w = (const float*)d_in[2];
  const float* wq   = (const float*)d_in[3];
  const float* wk   = (const float*)d_in[4];
  const float* wv   = (const float*)d_in[5];
  const float* wo   = (const float*)d_in[6];
  const float* ln2w = (const float*)d_in[7];
  const float* rww  = (const float*)d_in[8];
  const float* wgu  = (const float*)d_in[9];
  const float* wdn  = (const float*)d_in[10];
  const float* sgu  = (const float*)d_in[11];
  const float* sdn  = (const float*)d_in[12];
  float* out = (float*)d_out;

  char* ws = (char*)d_ws;
  size_t off = 0;
  auto alloc = [&](size_t b)->void*{ void* p = ws + off; off += (b + 255) & ~(size_t)255; return p; };

  u16* hbf     = (u16*)alloc((size_t)4096*1536*2);
  u16* qkv     = (u16*)alloc((size_t)33554432);
  u16* qbf  = qkv;
  u16* kbf  = qkv + (size_t)4096*1536;
  u16* vbf  = kbf + (size_t)4096*512;
  u16* aout = vbf + (size_t)4096*512;
  u16* act_moe = qkv;
  u16* act_sh  = (u16*)alloc((size_t)4096*1024*2);
  u16* vT      = (u16*)alloc((size_t)8*64*4096*2);
  int*   topi  = (int*)  alloc(4096*8*4);
  float* gatev = (float*)alloc(4096*8*4);
  int*   toks  = (int*)  alloc(4096*8*4);
  float* gts   = (float*)alloc(4096*8*4);
  int*   inv   = (int*)  alloc(4096*8*4);
  int*   cnt   = (int*)  alloc(512);
  int*   offs  = (int*)  alloc(512);
  int*   cur   = (int*)  alloc(512);
  u16* wqT  = (u16*)alloc((size_t)1536*1536*2);
  u16* wkT  = (u16*)alloc((size_t)512*1536*2);
  u16* wvT  = (u16*)alloc((size_t)512*1536*2);
  u16* woT  = (u16*)alloc((size_t)1536*1536*2);
  u16* sguT = (u16*)alloc((size_t)2048*1536*2);
  u16* sdnT = (u16*)alloc((size_t)1536*1024*2);
  u16* wguT = (u16*)alloc((size_t)32*1024*1536*2);
  u16* wdnT = (u16*)alloc((size_t)32*1536*512*2);
  float* hidden2 = out;
  u16*   h2bf = hbf;
  u16*   Opart = hbf;            // dead between qkv-proj and ln2
  float* mlb   = (float*)act_sh; // dead until shared gate_up
  u16*   part  = wguT;           // dead after moe gate_up consumes it (same stream order)

  // 0. weight convert+transpose pre-pass (bf16, [N][K])
  k_wt<<<dim3(48,48,1), 256,0,stream>>>(wq,  wqT,  1536,1536, 0,0);
  k_wt<<<dim3(16,48,1), 256,0,stream>>>(wk,  wkT,  1536,512,  0,0);
  k_wt<<<dim3(16,48,1), 256,0,stream>>>(wv,  wvT,  1536,512,  0,0);
  k_wt<<<dim3(48,48,1), 256,0,stream>>>(wo,  woT,  1536,1536, 0,0);
  k_wt<<<dim3(64,48,1), 256,0,stream>>>(sgu, sguT, 1536,2048, 0,0);
  k_wt<<<dim3(48,32,1), 256,0,stream>>>(sdn, sdnT, 1024,1536, 0,0);
  k_wt<<<dim3(32,48,32),256,0,stream>>>(wgu, wguT, 1536,1024, (long)1536*1024, (long)1536*1024);
  k_wt<<<dim3(48,16,32),256,0,stream>>>(wdn, wdnT, 512,1536,  (long)512*1536,  (long)512*1536);

  // 1. ln1
  k_rmsnorm<<<4096,192,0,stream>>>(hs, ln1w, hbf);
  // 2-4. q/k/v projections
  k_gemm<0,0><<<dim3(12,32,1),256,0,stream>>>(hbf,1536, wqT,0,1536, 4096,nullptr,nullptr,nullptr,nullptr,0, qbf,1536, nullptr,0, nullptr);
  k_gemm<0,0><<<dim3(4,32,1), 256,0,stream>>>(hbf,1536, wkT,0,1536, 4096,nullptr,nullptr,nullptr,nullptr,0, kbf,512,  nullptr,0, nullptr);
  k_gemm<0,0><<<dim3(4,32,1), 256,0,stream>>>(hbf,1536, wvT,0,1536, 4096,nullptr,nullptr,nullptr,nullptr,0, vbf,512,  nullptr,0, nullptr);
  // 5. rope, V transpose
  k_rope<<<16384,256,0,stream>>>(positions, qbf, kbf);
  k_vt<<<dim3(64,8,1),256,0,stream>>>(vbf, vT);
  // 6. flash attention with KV-split, then combine
  k_attn<<<dim3(768,1,1),256,0,stream>>>(qbf, kbf, vT, aout, Opart, mlb);
  k_comb<<<12288,256,0,stream>>>(Opart, mlb, aout);
  // 7. o-proj + residual -> hidden2 (in d_out)
  k_gemm<1,0><<<dim3(12,32,1),256,0,stream>>>(aout,1536, woT,0,1536, 4096,nullptr,nullptr,nullptr,nullptr,0, nullptr,0, hidden2,1536, hs);
  // 8. ln2
  k_rmsnorm<<<4096,192,0,stream>>>(hidden2, ln2w, h2bf);
  // 9. router + top-8
  k_router<<<4096,64,0,stream>>>(h2bf, rww, topi, gatev);
  // 10-13. expert grouping
  hipMemsetAsync(cnt, 0, 32*4, stream);
  k_hist<<<128,256,0,stream>>>(topi, cnt);
  k_scan<<<1,64,0,stream>>>(cnt, offs, cur);
  k_scatter<<<128,256,0,stream>>>(topi, gatev, cur, toks, gts, inv);
  // 14. moe gate_up + silu*mul (gathered rows)
  k_gemm<2,1><<<dim3(4,32,32),256,0,stream>>>(h2bf,1536, wguT,(long)1024*1536,1536, 0,cnt,offs,toks,nullptr, 512, act_moe,512, nullptr,0, nullptr);
  // 15. shared gate_up + silu*mul
  k_gemm<2,0><<<dim3(8,32,1),256,0,stream>>>(h2bf,1536, sguT,0,1536, 4096,nullptr,nullptr,nullptr,nullptr, 1024, act_sh,1024, nullptr,0, nullptr);
  // 16. shared down: out = hidden2 + shared*0.22
  k_gemm<1,0><<<dim3(12,32,1),256,0,stream>>>(act_sh,1024, sdnT,0,1024, 4096,nullptr,nullptr,nullptr,nullptr,0, nullptr,0, out,1536, out);
  // 17. moe down -> gate-scaled bf16 partials (overlaying dead wguT)
  k_gemm<5,0><<<dim3(12,32,32),256,0,stream>>>(act_moe,512, wdnT,(long)1536*512,512, 0,cnt,offs,nullptr,gts, 0, part,1536, nullptr,0, nullptr);
  // 18. sum the 8 partials per token onto out
  k_moesum<<<4096,192,0,stream>>>(part, inv, out);

  (void)in_sizes; (void)n_in; (void)out_size; (void)ws_size;
}

// Round 6
// 1100.531 us; speedup vs baseline: 2.4333x; 1.0264x over previous
//
#include <hip/hip_runtime.h>
#include <stdint.h>

using u16 = unsigned short;
using u32 = unsigned int;

typedef __attribute__((ext_vector_type(8))) short short8;
typedef __attribute__((ext_vector_type(4))) short short4v;
typedef __attribute__((ext_vector_type(4))) float f32x4;

#define MFMA16(a,b,c) __builtin_amdgcn_mfma_f32_16x16x32_bf16(a,b,c,0,0,0)

__device__ __forceinline__ u16 f2bf(float f){
  u32 u = __float_as_uint(f);
  u += 0x7fffu + ((u>>16)&1u);
  return (u16)(u>>16);
}
__device__ __forceinline__ float bf2f(u16 b){ return __uint_as_float(((u32)b)<<16); }

__device__ __forceinline__ void gload16(const void* g, void* l){
  __builtin_amdgcn_global_load_lds(
      (const __attribute__((address_space(1))) u32*)g,
      (__attribute__((address_space(3))) u32*)l, 16, 0, 0);
}

// 16-lane (DPP row) reductions — VALU only, no LDS traffic
__device__ __forceinline__ float red16_max(float x){
  float r;
  asm("v_max_f32 %0, %1, %1 row_ror:8 row_mask:0xf bank_mask:0xf" : "=v"(r) : "v"(x));
  asm("v_max_f32 %0, %1, %1 row_ror:4 row_mask:0xf bank_mask:0xf" : "=v"(r) : "v"(r));
  asm("v_max_f32 %0, %1, %1 row_ror:2 row_mask:0xf bank_mask:0xf" : "=v"(r) : "v"(r));
  asm("v_max_f32 %0, %1, %1 row_ror:1 row_mask:0xf bank_mask:0xf" : "=v"(r) : "v"(r));
  return r;
}
__device__ __forceinline__ float red16_sum(float x){
  float r;
  asm("v_add_f32 %0, %1, %1 row_ror:8 row_mask:0xf bank_mask:0xf" : "=v"(r) : "v"(x));
  asm("v_add_f32 %0, %1, %1 row_ror:4 row_mask:0xf bank_mask:0xf" : "=v"(r) : "v"(r));
  asm("v_add_f32 %0, %1, %1 row_ror:2 row_mask:0xf bank_mask:0xf" : "=v"(r) : "v"(r));
  asm("v_add_f32 %0, %1, %1 row_ror:1 row_mask:0xf bank_mask:0xf" : "=v"(r) : "v"(r));
  return r;
}

//------------------------------------------------------------------
// Weight prep: src f32 [K][N] -> dst bf16 [N][K]  (per blockIdx.z matrix)
__global__ __launch_bounds__(256) void k_wt(const float* __restrict__ src,
    u16* __restrict__ dst, int K, int N, long sstride, long dstride)
{
  __shared__ float tile[32][33];
  int nb = blockIdx.x*32, kb = blockIdx.y*32;
  const float* S = src + (long)blockIdx.z*sstride;
  u16* D = dst + (long)blockIdx.z*dstride;
  int tid = threadIdx.x;
  int r = tid>>3, c4 = (tid&7)*4;
  f32x4 v = *(const f32x4*)&S[(long)(kb+r)*N + nb + c4];
  tile[r][c4+0]=v[0]; tile[r][c4+1]=v[1]; tile[r][c4+2]=v[2]; tile[r][c4+3]=v[3];
  __syncthreads();
  short4v o;
  o[0]=(short)f2bf(tile[c4+0][r]);
  o[1]=(short)f2bf(tile[c4+1][r]);
  o[2]=(short)f2bf(tile[c4+2][r]);
  o[3]=(short)f2bf(tile[c4+3][r]);
  *(short4v*)&D[(long)(nb+r)*K + kb + c4] = o;
}

//------------------------------------------------------------------
// Interleaved weight prep for gate_up matrices:
// src f32 [K][N] (cols [0,halfN)=gate, [halfN,N)=up) -> dst bf16 [N][K] where
// combined row n: subtile s=n>>4, j=((n>>5)<<4)+(n&15); s even -> gate j, odd -> up j.
__global__ __launch_bounds__(256) void k_wti(const float* __restrict__ src,
    u16* __restrict__ dst, int K, int N, int halfN, long sstride, long dstride)
{
  __shared__ float tile[32][33];
  int nb = blockIdx.x*32, kb = blockIdx.y*32;
  const float* S = src + (long)blockIdx.z*sstride;
  u16* D = dst + (long)blockIdx.z*dstride;
  int tid = threadIdx.x;
  int r = tid>>3, c4 = (tid&7)*4;
  // combined col c (0..31) -> src col nb/2 + (c&15) + (c&16 ? halfN : 0)
  int scol = (nb>>1) + (c4&15) + ((c4&16)? halfN : 0);
  f32x4 v = *(const f32x4*)&S[(long)(kb+r)*N + scol];
  tile[r][c4+0]=v[0]; tile[r][c4+1]=v[1]; tile[r][c4+2]=v[2]; tile[r][c4+3]=v[3];
  __syncthreads();
  short4v o;
  o[0]=(short)f2bf(tile[c4+0][r]);
  o[1]=(short)f2bf(tile[c4+1][r]);
  o[2]=(short)f2bf(tile[c4+2][r]);
  o[3]=(short)f2bf(tile[c4+3][r]);
  *(short4v*)&D[(long)(nb+r)*K + kb + c4] = o;
}

//------------------------------------------------------------------
// V transpose: vbf [4096][8][64] bf16 -> vT [8][64][4096] bf16
__global__ __launch_bounds__(256) void k_vt(const u16* __restrict__ v,
                                            u16* __restrict__ vT)
{
  __shared__ u16 t_[64*72];
  int t0 = blockIdx.x*64, kvh = blockIdx.y;
  int tid = threadIdx.x;
  #pragma unroll
  for (int i=0;i<2;++i){
    int c = tid + i*256;
    int row = c>>3, dc = (c&7)*8;
    *(short8*)&t_[row*72 + dc] = *(const short8*)&v[(long)(t0+row)*512 + kvh*64 + dc];
  }
  __syncthreads();
  #pragma unroll
  for (int i=0;i<2;++i){
    int c = tid + i*256;
    int d = c>>3, tc = (c&7)*8;
    short8 o;
    #pragma unroll
    for (int j=0;j<8;++j) o[j] = (short)t_[(tc+j)*72 + d];
    *(short8*)&vT[(long)(kvh*64 + d)*4096 + t0 + tc] = o;
  }
}

//------------------------------------------------------------------
// RMSNorm: f32 [T,1536] -> bf16 [T,1536]
__global__ __launch_bounds__(192) void k_rmsnorm(const float* __restrict__ x,
                                                 const float* __restrict__ w,
                                                 u16* __restrict__ o)
{
  int t = blockIdx.x, tid = threadIdx.x;
  const float* xr = x + (size_t)t*1536 + tid*8;
  f32x4 a = *(const f32x4*)xr;
  f32x4 b = *(const f32x4*)(xr+4);
  float ss = a[0]*a[0]+a[1]*a[1]+a[2]*a[2]+a[3]*a[3]
           + b[0]*b[0]+b[1]*b[1]+b[2]*b[2]+b[3]*b[3];
  #pragma unroll
  for (int m=1;m<64;m<<=1) ss += __shfl_xor(ss,m);
  __shared__ float red[3];
  if ((tid&63)==0) red[tid>>6]=ss;
  __syncthreads();
  float inv = rsqrtf((red[0]+red[1]+red[2])*(1.0f/1536.0f)+1e-6f);
  const float* wp = w + tid*8;
  f32x4 wa = *(const f32x4*)wp;
  f32x4 wb = *(const f32x4*)(wp+4);
  u16* op = o + (size_t)t*1536 + tid*8;
  #pragma unroll
  for (int j=0;j<4;++j) op[j]   = f2bf(a[j]*inv*wa[j]);
  #pragma unroll
  for (int j=0;j<4;++j) op[j+4] = f2bf(b[j]*inv*wb[j]);
}

//------------------------------------------------------------------
// m97-style 128x128 GEMM, 2 staged matrices in all modes.
// MODE 0: Cb = bf16(acc)
// MODE 1: Cf[idx] = resid[idx] + acc*0.22
// MODE 5: Cb[roff+gr] = bf16(acc * gates[roff+gr])   (sorted partial rows)
// MODE 6: interleaved gate/up B; epilogue silu(acc[m][2k])*acc[m][2k+1],
//         out col = (col0>>1) + (wc>>1) + k*16 + lr, ldcb = halfN of the op.
template<int MODE, int GATHER>
__global__ __launch_bounds__(256,3) void k_gemm(
    const u16* __restrict__ A, int lda,
    const u16* __restrict__ Bt, long strideB, int K,
    int Mfix, const int* __restrict__ cnts, const int* __restrict__ offs,
    const int* __restrict__ toks, const float* __restrict__ gates,
    u16* __restrict__ Cb, int ldcb,
    float* __restrict__ Cf, int ldcf,
    const float* __restrict__ resid)
{
  int e = blockIdx.z;
  int M = cnts ? cnts[e] : Mfix;
  int m0 = blockIdx.y*128;
  if (m0 >= M) return;
  int roff = offs ? offs[e] : 0;
  const u16* Bp = Bt + (long)e*strideB;
  int col0 = blockIdx.x*128;

  __shared__ u16 Ash[4096];
  __shared__ u16 Bsh[4096];

  int tid = threadIdx.x, wv = tid>>6, lane = tid&63;
  int lr = lane&15, lg = lane>>4;
  int wr = (wv>>1)*64, wc = (wv&1)*64;

  int row0 = tid>>2, kc = (tid&3)*8;
  int gr0 = min(m0 + row0,      M-1);
  int gr1 = min(m0 + row0 + 64, M-1);
  int ar0, ar1;
  if (GATHER){ ar0 = toks[roff + gr0]; ar1 = toks[roff + gr1]; }
  else       { ar0 = roff + gr0;       ar1 = roff + gr1; }
  const u16* ap0 = A + (long)ar0*lda + kc;
  const u16* ap1 = A + (long)ar1*lda + kc;
  const u16* bp0 = Bp + (long)(col0 + row0)*K + kc;
  const u16* bp1 = bp0 + (long)64*K;

  u16* As0 = &Ash[wv*512];  u16* As1 = &Ash[2048 + wv*512];
  u16* Bs0 = &Bsh[wv*512];  u16* Bs1 = &Bsh[2048 + wv*512];

  f32x4 acc[4][4];
  #pragma unroll
  for (int m=0;m<4;++m)
    #pragma unroll
    for (int n=0;n<4;++n)
      acc[m][n] = (f32x4){0.f,0.f,0.f,0.f};

  int nk = K>>5;
  for (int kt=0; kt<nk; ++kt){
    __syncthreads();
    gload16(ap0, As0); gload16(ap1, As1);
    gload16(bp0, Bs0); gload16(bp1, Bs1);
    ap0 += 32; ap1 += 32; bp0 += 32; bp1 += 32;
    __syncthreads();

    short8 af[4], b1[4];
    #pragma unroll
    for (int m=0;m<4;++m) af[m] = *(const short8*)&Ash[(wr+m*16+lr)*32 + lg*8];
    #pragma unroll
    for (int n=0;n<4;++n) b1[n] = *(const short8*)&Bsh[(wc+n*16+lr)*32 + lg*8];
    #pragma unroll
    for (int m=0;m<4;++m)
      #pragma unroll
      for (int n=0;n<4;++n)
        acc[m][n] = MFMA16(af[m], b1[n], acc[m][n]);
  }

  if constexpr(MODE==6){
    #pragma unroll
    for (int m=0;m<4;++m)
      #pragma unroll
      for (int np=0;np<2;++np)
        #pragma unroll
        for (int rr=0;rr<4;++rr){
          int row = wr + m*16 + lg*4 + rr;
          int gr = m0 + row;
          if (gr >= M) continue;
          float g = acc[m][2*np][rr];
          float u = acc[m][2*np+1][rr];
          float s = g/(1.f+__expf(-g))*u;
          int j = (wc>>1) + np*16 + lr;     // local 0..63
          Cb[(long)(roff+gr)*ldcb + (col0>>1) + j] = f2bf(s);
        }
  } else {
    #pragma unroll
    for (int m=0;m<4;++m)
      #pragma unroll
      for (int n=0;n<4;++n)
        #pragma unroll
        for (int rr=0;rr<4;++rr){
          int row = wr + m*16 + lg*4 + rr;
          int gr = m0 + row;
          if (gr >= M) continue;
          int col = wc + n*16 + lr;
          float va = acc[m][n][rr];
          if constexpr(MODE==0){
            Cb[(long)(roff+gr)*ldcb + col0 + col] = f2bf(va);
          } else if constexpr(MODE==1){
            long idx = (long)gr*ldcf + col0 + col;
            Cf[idx] = resid[idx] + va*0.22f;
          } else if constexpr(MODE==5){
            float gt = gates[roff+gr];
            Cb[(long)(roff+gr)*ldcb + col0 + col] = f2bf(va*gt);
          }
        }
  }
}

//------------------------------------------------------------------
// MoE sum: out[t] += sum_{kk} part[inv[t*8+kk]]  (partials pre-scaled)
__global__ __launch_bounds__(192) void k_moesum(const u16* __restrict__ part,
    const int* __restrict__ inv, float* __restrict__ out)
{
  int t = blockIdx.x, tid = threadIdx.x;
  int c = tid*8;
  float s[8] = {0.f,0.f,0.f,0.f,0.f,0.f,0.f,0.f};
  #pragma unroll
  for (int kk=0;kk<8;++kk){
    int slot = inv[t*8+kk];
    short8 v = *(const short8*)&part[(long)slot*1536 + c];
    #pragma unroll
    for (int j=0;j<8;++j) s[j] += bf2f((u16)v[j]);
  }
  float* op = out + (long)t*1536 + c;
  f32x4 o0 = *(const f32x4*)op;
  f32x4 o1 = *(const f32x4*)(op+4);
  #pragma unroll
  for (int j=0;j<4;++j){ o0[j] += s[j]; o1[j] += s[j+4]; }
  *(f32x4*)op = o0;
  *(f32x4*)(op+4) = o1;
}

//------------------------------------------------------------------
// RoPE in-place on q (T,24,64) and k (T,8,64)
__global__ __launch_bounds__(256) void k_rope(const int* __restrict__ pos,
    u16* __restrict__ qb, u16* __restrict__ kb)
{
  int gid = blockIdx.x*256 + threadIdx.x;
  int t = gid >> 10, p = gid & 1023;
  int j = p & 31;
  float invf = __expf(-(float)j * 0.28782313662425574f);
  float ang = (float)pos[t] * invf;
  float sn, cs; __sincosf(ang, &sn, &cs);
  u16* base;
  if (p < 768) base = qb + (long)t*1536 + (p>>5)*64;
  else         base = kb + (long)t*512  + ((p-768)>>5)*64;
  float x1 = bf2f(base[j]), x2 = bf2f(base[j+32]);
  base[j]    = f2bf(x1*cs - x2*sn);
  base[j+32] = f2bf(x2*cs + x1*sn);
}

//------------------------------------------------------------------
// Causal flash attention with KV-split (unchanged)
__global__ __launch_bounds__(256,3) void k_attn(const u16* __restrict__ qg,
    const u16* __restrict__ kg, const u16* __restrict__ vT,
    u16* __restrict__ og, u16* __restrict__ Opart, float* __restrict__ mlb)
{
  int bid = blockIdx.x;               // 768 = 96 x 8
  int kvh = bid & 7;
  int ii = bid >> 3;
  int qt, kt0, kt1, chunk; bool single;
  if (ii < 32)      { qt = 32+ii;        chunk = 0; kt0 = 0;  kt1 = 32;   single = false; }
  else if (ii < 64) { qt = 63-(ii-32);   chunk = 1; kt0 = 32; kt1 = qt+1; single = false; }
  else              { qt = 31-(ii-64);   chunk = 0; kt0 = 0;  kt1 = qt+1; single = true;  }

  int tid = threadIdx.x, wv = tid>>6, lane = tid&63;
  int lr = lane&15, lg = lane>>4;
  __shared__ u16 Ksh[64*72];
  __shared__ u16 Vsh[64*72];
  __shared__ u16 Psh[4][16*72];
  int q0 = qt*64;
  int qrow = q0 + wv*16 + lr;
  short8 qf[3][2];
  #pragma unroll
  for (int hh=0;hh<3;++hh)
    #pragma unroll
    for (int c=0;c<2;++c)
      qf[hh][c] = *(const short8*)&qg[(long)qrow*1536 + (kvh*3+hh)*64 + c*32 + lg*8];

  float m_[3][4], l_[3][4];
  f32x4 Ot[3][4];
  #pragma unroll
  for (int hh=0;hh<3;++hh)
    #pragma unroll
    for (int r=0;r<4;++r){ m_[hh][r]=-1e30f; l_[hh][r]=0.f; }
  #pragma unroll
  for (int hh=0;hh<3;++hh)
    #pragma unroll
    for (int d=0;d<4;++d) Ot[hh][d]=(f32x4){0.f,0.f,0.f,0.f};

  int srow = tid>>3, sdc = (tid&7)*8;
  short8 kreg[2], vreg[2];
  auto loadKV = [&](int kt){
    #pragma unroll
    for (int i=0;i<2;++i){
      int row = srow + i*32;
      kreg[i] = *(const short8*)&kg[(long)(kt*64+row)*512 + kvh*64 + sdc];
      vreg[i] = *(const short8*)&vT[(long)(kvh*64 + row)*4096 + kt*64 + sdc];
    }
  };
  loadKV(kt0);

  for (int kt=kt0; kt<kt1; ++kt){
    __syncthreads();
    #pragma unroll
    for (int i=0;i<2;++i){
      int row = srow + i*32;
      *(short8*)&Ksh[row*72 + sdc] = kreg[i];
      *(short8*)&Vsh[row*72 + sdc] = vreg[i];
    }
    __syncthreads();
    if (kt < kt1-1) loadKV(kt+1);
    bool diag = (kt==qt);

    #pragma unroll
    for (int hh=0;hh<3;++hh){
      f32x4 S[4];
      #pragma unroll
      for (int n=0;n<4;++n) S[n]=(f32x4){0.f,0.f,0.f,0.f};
      #pragma unroll
      for (int n=0;n<4;++n)
        #pragma unroll
        for (int c=0;c<2;++c){
          short8 kf = *(const short8*)&Ksh[(n*16+lr)*72 + c*32 + lg*8];
          S[n] = MFMA16(qf[hh][c], kf, S[n]);
        }

      float rmax[4] = {-1e30f,-1e30f,-1e30f,-1e30f};
      #pragma unroll
      for (int n=0;n<4;++n)
        #pragma unroll
        for (int r=0;r<4;++r){
          float sv = S[n][r]*0.015625f;
          if (diag){
            int colg = n*16 + lr;
            int rowg = wv*16 + lg*4 + r;
            if (colg > rowg) sv = -1e30f;
          }
          S[n][r] = sv;
          rmax[r] = fmaxf(rmax[r], sv);
        }
      #pragma unroll
      for (int r=0;r<4;++r) rmax[r] = red16_max(rmax[r]);

      float alpha[4], rsum[4];
      #pragma unroll
      for (int r=0;r<4;++r){
        float mn = fmaxf(m_[hh][r], rmax[r]);
        alpha[r] = __expf(m_[hh][r]-mn);
        m_[hh][r] = mn;
        rsum[r] = 0.f;
      }
      #pragma unroll
      for (int n=0;n<4;++n)
        #pragma unroll
        for (int r=0;r<4;++r){
          float pv = __expf(S[n][r]-m_[hh][r]);
          S[n][r]=pv; rsum[r]+=pv;
        }
      #pragma unroll
      for (int r=0;r<4;++r) rsum[r] = red16_sum(rsum[r]);
      #pragma unroll
      for (int r=0;r<4;++r) l_[hh][r] = l_[hh][r]*alpha[r] + rsum[r];
      #pragma unroll
      for (int d=0;d<4;++d)
        #pragma unroll
        for (int r=0;r<4;++r) Ot[hh][d][r] *= alpha[r];

      #pragma unroll
      for (int n=0;n<4;++n)
        #pragma unroll
        for (int r=0;r<4;++r)
          Psh[wv][(lg*4+r)*72 + n*16 + lr] = f2bf(S[n][r]);
      #pragma unroll
      for (int c=0;c<2;++c){
        short8 pf = *(const short8*)&Psh[wv][lr*72 + c*32 + lg*8];
        #pragma unroll
        for (int d=0;d<4;++d){
          short8 vf = *(const short8*)&Vsh[(d*16+lr)*72 + c*32 + lg*8];
          Ot[hh][d] = MFMA16(pf, vf, Ot[hh][d]);
        }
      }
    }
  }

  if (single){
    #pragma unroll
    for (int hh=0;hh<3;++hh)
      #pragma unroll
      for (int d=0;d<4;++d)
        #pragma unroll
        for (int r=0;r<4;++r){
          int t = q0 + wv*16 + lg*4 + r;
          og[(long)t*1536 + (kvh*3+hh)*64 + d*16 + lr] = f2bf(Ot[hh][d][r]/l_[hh][r]);
        }
  } else {
    #pragma unroll
    for (int hh=0;hh<3;++hh){
      int h = kvh*3+hh;
      #pragma unroll
      for (int r=0;r<4;++r){
        int t = q0 + wv*16 + lg*4 + r;
        long slot = ((long)(t-2048)*24 + h)*2 + chunk;
        #pragma unroll
        for (int d=0;d<4;++d)
          Opart[slot*64 + d*16 + lr] = f2bf(Ot[hh][d][r]);
        if (lr==0){ mlb[slot*2] = m_[hh][r]; mlb[slot*2+1] = l_[hh][r]; }
      }
    }
  }
}

//------------------------------------------------------------------
__global__ __launch_bounds__(256) void k_comb(const u16* __restrict__ Opart,
    const float* __restrict__ mlb, u16* __restrict__ og)
{
  int gid = blockIdx.x*256 + threadIdx.x;
  int d = gid & 63;
  long rowi = gid >> 6;
  long s0 = rowi*2, s1 = s0+1;
  float m0 = mlb[s0*2], l0 = mlb[s0*2+1];
  float m1 = mlb[s1*2], l1 = mlb[s1*2+1];
  float M = fmaxf(m0,m1);
  float w0 = __expf(m0-M), w1 = __expf(m1-M);
  float o = (bf2f(Opart[s0*64+d])*w0 + bf2f(Opart[s1*64+d])*w1) / (l0*w0 + l1*w1);
  int t = 2048 + (int)(rowi/24), h = (int)(rowi - (rowi/24)*24);
  og[(long)t*1536 + h*64 + d] = f2bf(o);
}

//------------------------------------------------------------------
__global__ __launch_bounds__(64) void k_router(const u16* __restrict__ h2,
    const float* __restrict__ rw, int* __restrict__ topi, float* __restrict__ gatev)
{
  int t = blockIdx.x, lane = threadIdx.x;
  int e = lane & 31, hf = lane >> 5;
  const u16* hr = h2 + (size_t)t*1536 + hf*768;
  const float* wp = rw + (long)hf*768*32 + e;
  float s = 0.f;
  for (int d=0; d<768; ++d)
    s += bf2f(hr[d]) * wp[(long)d*32];
  s += __shfl_xor(s, 32);
  __shared__ float lgt[32];
  if (lane < 32) lgt[e] = s;
  __syncthreads();
  if (lane==0){
    u32 msk=0; float tv[8]; int ti[8];
    for (int kk=0;kk<8;++kk){
      float best=-1e30f; int bi=0;
      for (int j2=0;j2<32;++j2)
        if (!((msk>>j2)&1u) && lgt[j2] > best){ best=lgt[j2]; bi=j2; }
      msk |= 1u<<bi; tv[kk]=best; ti[kk]=bi;
    }
    float mx = tv[0], ssum = 0.f, ge[8];
    for (int kk=0;kk<8;++kk){ ge[kk]=__expf(tv[kk]-mx); ssum+=ge[kk]; }
    float isum = 1.f/ssum;
    for (int kk=0;kk<8;++kk){ topi[t*8+kk]=ti[kk]; gatev[t*8+kk]=ge[kk]*isum; }
  }
}

__global__ void k_hist(const int* __restrict__ topi, int* __restrict__ cnt){
  int i = blockIdx.x*256 + threadIdx.x;
  if (i < 4096*8) atomicAdd(&cnt[topi[i]], 1);
}
__global__ void k_scan(const int* __restrict__ cnt, int* __restrict__ offs, int* __restrict__ cur){
  if (threadIdx.x==0 && blockIdx.x==0){
    int a=0;
    for (int e2=0;e2<32;++e2){ offs[e2]=a; cur[e2]=a; a+=cnt[e2]; }
  }
}
__global__ void k_scatter(const int* __restrict__ topi, const float* __restrict__ gatev,
    int* __restrict__ cur, int* __restrict__ toks, float* __restrict__ gts,
    int* __restrict__ inv){
  int i = blockIdx.x*256 + threadIdx.x;
  if (i < 4096*8){
    int e2 = topi[i];
    int p = atomicAdd(&cur[e2], 1);
    toks[p] = i>>3;
    gts[p] = gatev[i]*0.22f;
    inv[i] = p;
  }
}

//------------------------------------------------------------------
extern "C" void kernel_launch(void* const* d_in, const int* in_sizes, int n_in,
                              void* d_out, int out_size, void* d_ws, size_t ws_size,
                              hipStream_t stream)
{
  const int*   positions = (const int*)  d_in[0];
  const float* hs   = (const float*)d_in[1];
  const float* ln1w = (const float*)d_in[2];
  const float* wq   = (const float*)d_in[3];
  const float* wk   = (const float*)d_in[4];
  const float* wv   = (const float*)d_in[5];
  const float* wo   = (const float*)d_in[6];
  const float* ln2w = (const float*)d_in[7];
  const float* rww  = (const float*)d_in[8];
  const float* wgu  = (const float*)d_in[9];
  const float* wdn  = (const float*)d_in[10];
  const float* sgu  = (const float*)d_in[11];
  const float* sdn  = (const float*)d_in[12];
  float* out = (float*)d_out;

  char* ws = (char*)d_ws;
  size_t off = 0;
  auto alloc = [&](size_t b)->void*{ void* p = ws + off; off += (b + 255) & ~(size_t)255; return p; };

  u16* hbf     = (u16*)alloc((size_t)4096*1536*2);
  u16* qkv     = (u16*)alloc((size_t)33554432);
  u16* qbf  = qkv;
  u16* kbf  = qkv + (size_t)4096*1536;
  u16* vbf  = kbf + (size_t)4096*512;
  u16* aout = vbf + (size_t)4096*512;
  u16* act_moe = qkv;
  u16* act_sh  = (u16*)alloc((size_t)4096*1024*2);
  u16* vT      = (u16*)alloc((size_t)8*64*4096*2);
  int*   topi  = (int*)  alloc(4096*8*4);
  float* gatev = (float*)alloc(4096*8*4);
  int*   toks  = (int*)  alloc(4096*8*4);
  float* gts   = (float*)alloc(4096*8*4);
  int*   inv   = (int*)  alloc(4096*8*4);
  int*   cnt   = (int*)  alloc(512);
  int*   offs  = (int*)  alloc(512);
  int*   cur   = (int*)  alloc(512);
  u16* wqT  = (u16*)alloc((size_t)1536*1536*2);
  u16* wkT  = (u16*)alloc((size_t)512*1536*2);
  u16* wvT  = (u16*)alloc((size_t)512*1536*2);
  u16* woT  = (u16*)alloc((size_t)1536*1536*2);
  u16* sguT = (u16*)alloc((size_t)2048*1536*2);
  u16* sdnT = (u16*)alloc((size_t)1536*1024*2);
  u16* wguT = (u16*)alloc((size_t)32*1024*1536*2);
  u16* wdnT = (u16*)alloc((size_t)32*1536*512*2);
  float* hidden2 = out;
  u16*   h2bf = hbf;
  u16*   Opart = hbf;            // dead between qkv-proj and ln2
  float* mlb   = (float*)act_sh; // dead until shared gate_up
  u16*   part  = wguT;           // dead after moe gate_up consumes it

  // 0. weight convert+transpose pre-pass (bf16, [N][K]); gate_up matrices interleaved
  k_wt <<<dim3(48,48,1), 256,0,stream>>>(wq,  wqT,  1536,1536, 0,0);
  k_wt <<<dim3(16,48,1), 256,0,stream>>>(wk,  wkT,  1536,512,  0,0);
  k_wt <<<dim3(16,48,1), 256,0,stream>>>(wv,  wvT,  1536,512,  0,0);
  k_wt <<<dim3(48,48,1), 256,0,stream>>>(wo,  woT,  1536,1536, 0,0);
  k_wti<<<dim3(64,48,1), 256,0,stream>>>(sgu, sguT, 1536,2048,1024, 0,0);
  k_wt <<<dim3(48,32,1), 256,0,stream>>>(sdn, sdnT, 1024,1536, 0,0);
  k_wti<<<dim3(32,48,32),256,0,stream>>>(wgu, wguT, 1536,1024,512, (long)1536*1024, (long)1536*1024);
  k_wt <<<dim3(48,16,32),256,0,stream>>>(wdn, wdnT, 512,1536,  (long)512*1536,  (long)512*1536);

  // 1. ln1
  k_rmsnorm<<<4096,192,0,stream>>>(hs, ln1w, hbf);
  // 2-4. q/k/v projections
  k_gemm<0,0><<<dim3(12,32,1),256,0,stream>>>(hbf,1536, wqT,0,1536, 4096,nullptr,nullptr,nullptr,nullptr, qbf,1536, nullptr,0, nullptr);
  k_gemm<0,0><<<dim3(4,32,1), 256,0,stream>>>(hbf,1536, wkT,0,1536, 4096,nullptr,nullptr,nullptr,nullptr, kbf,512,  nullptr,0, nullptr);
  k_gemm<0,0><<<dim3(4,32,1), 256,0,stream>>>(hbf,1536, wvT,0,1536, 4096,nullptr,nullptr,nullptr,nullptr, vbf,512,  nullptr,0, nullptr);
  // 5. rope, V transpose
  k_rope<<<16384,256,0,stream>>>(positions, qbf, kbf);
  k_vt<<<dim3(64,8,1),256,0,stream>>>(vbf, vT);
  // 6. flash attention with KV-split, then combine
  k_attn<<<dim3(768,1,1),256,0,stream>>>(qbf, kbf, vT, aout, Opart, mlb);
  k_comb<<<12288,256,0,stream>>>(Opart, mlb, aout);
  // 7. o-proj + residual -> hidden2 (in d_out)
  k_gemm<1,0><<<dim3(12,32,1),256,0,stream>>>(aout,1536, woT,0,1536, 4096,nullptr,nullptr,nullptr,nullptr, nullptr,0, hidden2,1536, hs);
  // 8. ln2
  k_rmsnorm<<<4096,192,0,stream>>>(hidden2, ln2w, h2bf);
  // 9. router + top-8
  k_router<<<4096,64,0,stream>>>(h2bf, rww, topi, gatev);
  // 10-13. expert grouping
  hipMemsetAsync(cnt, 0, 32*4, stream);
  k_hist<<<128,256,0,stream>>>(topi, cnt);
  k_scan<<<1,64,0,stream>>>(cnt, offs, cur);
  k_scatter<<<128,256,0,stream>>>(topi, gatev, cur, toks, gts, inv);
  // 14. moe gate_up + silu*mul (gathered rows, interleaved B)
  k_gemm<6,1><<<dim3(8,32,32),256,0,stream>>>(h2bf,1536, wguT,(long)1024*1536,1536, 0,cnt,offs,toks,nullptr, act_moe,512, nullptr,0, nullptr);
  // 15. shared gate_up + silu*mul (interleaved B)
  k_gemm<6,0><<<dim3(16,32,1),256,0,stream>>>(h2bf,1536, sguT,0,1536, 4096,nullptr,nullptr,nullptr,nullptr, act_sh,1024, nullptr,0, nullptr);
  // 16. shared down: out = hidden2 + shared*0.22
  k_gemm<1,0><<<dim3(12,32,1),256,0,stream>>>(act_sh,1024, sdnT,0,1024, 4096,nullptr,nullptr,nullptr,nullptr, nullptr,0, out,1536, out);
  // 17. moe down -> gate-scaled bf16 partials (overlaying dead wguT)
  k_gemm<5,0><<<dim3(12,32,32),256,0,stream>>>(act_moe,512, wdnT,(long)1536*512,512, 0,cnt,offs,nullptr,gts, part,1536, nullptr,0, nullptr);
  // 18. sum the 8 partials per token onto out
  k_moesum<<<4096,192,0,stream>>>(part, inv, out);

  (void)in_sizes; (void)n_in; (void)out_size; (void)ws_size;
}

// Round 8
// 1024.886 us; speedup vs baseline: 2.6129x; 1.0738x over previous
//
#include <hip/hip_runtime.h>
#include <stdint.h>

using u16 = unsigned short;
using u32 = unsigned int;

typedef __attribute__((ext_vector_type(8))) short short8;
typedef __attribute__((ext_vector_type(4))) short short4v;
typedef __attribute__((ext_vector_type(4))) float f32x4;

#define MFMA16(a,b,c) __builtin_amdgcn_mfma_f32_16x16x32_bf16(a,b,c,0,0,0)

__device__ __forceinline__ u16 f2bf(float f){
  u32 u = __float_as_uint(f);
  u += 0x7fffu + ((u>>16)&1u);
  return (u16)(u>>16);
}
__device__ __forceinline__ float bf2f(u16 b){ return __uint_as_float(((u32)b)<<16); }

__device__ __forceinline__ void gload16(const void* g, void* l){
  __builtin_amdgcn_global_load_lds(
      (const __attribute__((address_space(1))) u32*)g,
      (__attribute__((address_space(3))) u32*)l, 16, 0, 0);
}

// 16-lane (DPP row) reductions — VALU only, no LDS traffic
__device__ __forceinline__ float red16_max(float x){
  float r;
  asm("v_max_f32 %0, %1, %1 row_ror:8 row_mask:0xf bank_mask:0xf" : "=v"(r) : "v"(x));
  asm("v_max_f32 %0, %1, %1 row_ror:4 row_mask:0xf bank_mask:0xf" : "=v"(r) : "v"(r));
  asm("v_max_f32 %0, %1, %1 row_ror:2 row_mask:0xf bank_mask:0xf" : "=v"(r) : "v"(r));
  asm("v_max_f32 %0, %1, %1 row_ror:1 row_mask:0xf bank_mask:0xf" : "=v"(r) : "v"(r));
  return r;
}
__device__ __forceinline__ float red16_sum(float x){
  float r;
  asm("v_add_f32 %0, %1, %1 row_ror:8 row_mask:0xf bank_mask:0xf" : "=v"(r) : "v"(x));
  asm("v_add_f32 %0, %1, %1 row_ror:4 row_mask:0xf bank_mask:0xf" : "=v"(r) : "v"(r));
  asm("v_add_f32 %0, %1, %1 row_ror:2 row_mask:0xf bank_mask:0xf" : "=v"(r) : "v"(r));
  asm("v_add_f32 %0, %1, %1 row_ror:1 row_mask:0xf bank_mask:0xf" : "=v"(r) : "v"(r));
  return r;
}

//------------------------------------------------------------------
// Weight prep: src f32 [K][N] -> dst bf16 [N][K]  (per blockIdx.z matrix)
__global__ __launch_bounds__(256) void k_wt(const float* __restrict__ src,
    u16* __restrict__ dst, int K, int N, long sstride, long dstride)
{
  __shared__ float tile[32][33];
  int nb = blockIdx.x*32, kb = blockIdx.y*32;
  const float* S = src + (long)blockIdx.z*sstride;
  u16* D = dst + (long)blockIdx.z*dstride;
  int tid = threadIdx.x;
  int r = tid>>3, c4 = (tid&7)*4;
  f32x4 v = *(const f32x4*)&S[(long)(kb+r)*N + nb + c4];
  tile[r][c4+0]=v[0]; tile[r][c4+1]=v[1]; tile[r][c4+2]=v[2]; tile[r][c4+3]=v[3];
  __syncthreads();
  short4v o;
  o[0]=(short)f2bf(tile[c4+0][r]);
  o[1]=(short)f2bf(tile[c4+1][r]);
  o[2]=(short)f2bf(tile[c4+2][r]);
  o[3]=(short)f2bf(tile[c4+3][r]);
  *(short4v*)&D[(long)(nb+r)*K + kb + c4] = o;
}

//------------------------------------------------------------------
// Interleaved weight prep for gate_up matrices (16-col subtile interleave)
__global__ __launch_bounds__(256) void k_wti(const float* __restrict__ src,
    u16* __restrict__ dst, int K, int N, int halfN, long sstride, long dstride)
{
  __shared__ float tile[32][33];
  int nb = blockIdx.x*32, kb = blockIdx.y*32;
  const float* S = src + (long)blockIdx.z*sstride;
  u16* D = dst + (long)blockIdx.z*dstride;
  int tid = threadIdx.x;
  int r = tid>>3, c4 = (tid&7)*4;
  int scol = (nb>>1) + (c4&15) + ((c4&16)? halfN : 0);
  f32x4 v = *(const f32x4*)&S[(long)(kb+r)*N + scol];
  tile[r][c4+0]=v[0]; tile[r][c4+1]=v[1]; tile[r][c4+2]=v[2]; tile[r][c4+3]=v[3];
  __syncthreads();
  short4v o;
  o[0]=(short)f2bf(tile[c4+0][r]);
  o[1]=(short)f2bf(tile[c4+1][r]);
  o[2]=(short)f2bf(tile[c4+2][r]);
  o[3]=(short)f2bf(tile[c4+3][r]);
  *(short4v*)&D[(long)(nb+r)*K + kb + c4] = o;
}

//------------------------------------------------------------------
// V transpose: v (stride 2560, offset pre-applied) [4096][..64..] -> vT [8][64][4096]
__global__ __launch_bounds__(256) void k_vt(const u16* __restrict__ v,
                                            u16* __restrict__ vT)
{
  __shared__ u16 t_[64*72];
  int t0 = blockIdx.x*64, kvh = blockIdx.y;
  int tid = threadIdx.x;
  #pragma unroll
  for (int i=0;i<2;++i){
    int c = tid + i*256;
    int row = c>>3, dc = (c&7)*8;
    *(short8*)&t_[row*72 + dc] = *(const short8*)&v[(long)(t0+row)*2560 + kvh*64 + dc];
  }
  __syncthreads();
  #pragma unroll
  for (int i=0;i<2;++i){
    int c = tid + i*256;
    int d = c>>3, tc = (c&7)*8;
    short8 o;
    #pragma unroll
    for (int j=0;j<8;++j) o[j] = (short)t_[(tc+j)*72 + d];
    *(short8*)&vT[(long)(kvh*64 + d)*4096 + t0 + tc] = o;
  }
}

//------------------------------------------------------------------
// RMSNorm: f32 [T,1536] -> bf16 [T,1536]
__global__ __launch_bounds__(192) void k_rmsnorm(const float* __restrict__ x,
                                                 const float* __restrict__ w,
                                                 u16* __restrict__ o)
{
  int t = blockIdx.x, tid = threadIdx.x;
  const float* xr = x + (size_t)t*1536 + tid*8;
  f32x4 a = *(const f32x4*)xr;
  f32x4 b = *(const f32x4*)(xr+4);
  float ss = a[0]*a[0]+a[1]*a[1]+a[2]*a[2]+a[3]*a[3]
           + b[0]*b[0]+b[1]*b[1]+b[2]*b[2]+b[3]*b[3];
  #pragma unroll
  for (int m=1;m<64;m<<=1) ss += __shfl_xor(ss,m);
  __shared__ float red[3];
  if ((tid&63)==0) red[tid>>6]=ss;
  __syncthreads();
  float inv = rsqrtf((red[0]+red[1]+red[2])*(1.0f/1536.0f)+1e-6f);
  const float* wp = w + tid*8;
  f32x4 wa = *(const f32x4*)wp;
  f32x4 wb = *(const f32x4*)(wp+4);
  u16* op = o + (size_t)t*1536 + tid*8;
  #pragma unroll
  for (int j=0;j<4;++j) op[j]   = f2bf(a[j]*inv*wa[j]);
  #pragma unroll
  for (int j=0;j<4;++j) op[j+4] = f2bf(b[j]*inv*wb[j]);
}

//------------------------------------------------------------------
// m97-style 128x128 GEMM, 2 staged matrices in all modes.
// MODE 0: Cb = bf16(acc)
// MODE 1: Cf[idx] = resid[idx] + acc*0.22
// MODE 5: Cb[roff+gr] = bf16(acc * gates[roff+gr])   (sorted partial rows)
// MODE 6: interleaved gate/up B; silu(acc[m][2k])*acc[m][2k+1]
template<int MODE, int GATHER>
__global__ __launch_bounds__(256,3) void k_gemm(
    const u16* __restrict__ A, int lda,
    const u16* __restrict__ Bt, long strideB, int K,
    int Mfix, const int* __restrict__ cnts, const int* __restrict__ offs,
    const int* __restrict__ toks, const float* __restrict__ gates,
    u16* __restrict__ Cb, int ldcb,
    float* __restrict__ Cf, int ldcf,
    const float* __restrict__ resid)
{
  int e = blockIdx.z;
  int M = cnts ? cnts[e] : Mfix;
  int m0 = blockIdx.y*128;
  if (m0 >= M) return;
  int roff = offs ? offs[e] : 0;
  const u16* Bp = Bt + (long)e*strideB;
  int col0 = blockIdx.x*128;

  __shared__ u16 Ash[4096];
  __shared__ u16 Bsh[4096];

  int tid = threadIdx.x, wv = tid>>6, lane = tid&63;
  int lr = lane&15, lg = lane>>4;
  int wr = (wv>>1)*64, wc = (wv&1)*64;

  int row0 = tid>>2, kc = (tid&3)*8;
  int gr0 = min(m0 + row0,      M-1);
  int gr1 = min(m0 + row0 + 64, M-1);
  int ar0, ar1;
  if (GATHER){ ar0 = toks[roff + gr0]; ar1 = toks[roff + gr1]; }
  else       { ar0 = roff + gr0;       ar1 = roff + gr1; }
  const u16* ap0 = A + (long)ar0*lda + kc;
  const u16* ap1 = A + (long)ar1*lda + kc;
  const u16* bp0 = Bp + (long)(col0 + row0)*K + kc;
  const u16* bp1 = bp0 + (long)64*K;

  u16* As0 = &Ash[wv*512];  u16* As1 = &Ash[2048 + wv*512];
  u16* Bs0 = &Bsh[wv*512];  u16* Bs1 = &Bsh[2048 + wv*512];

  f32x4 acc[4][4];
  #pragma unroll
  for (int m=0;m<4;++m)
    #pragma unroll
    for (int n=0;n<4;++n)
      acc[m][n] = (f32x4){0.f,0.f,0.f,0.f};

  int nk = K>>5;
  for (int kt=0; kt<nk; ++kt){
    __syncthreads();
    gload16(ap0, As0); gload16(ap1, As1);
    gload16(bp0, Bs0); gload16(bp1, Bs1);
    ap0 += 32; ap1 += 32; bp0 += 32; bp1 += 32;
    __syncthreads();

    short8 af[4], b1[4];
    #pragma unroll
    for (int m=0;m<4;++m) af[m] = *(const short8*)&Ash[(wr+m*16+lr)*32 + lg*8];
    #pragma unroll
    for (int n=0;n<4;++n) b1[n] = *(const short8*)&Bsh[(wc+n*16+lr)*32 + lg*8];
    #pragma unroll
    for (int m=0;m<4;++m)
      #pragma unroll
      for (int n=0;n<4;++n)
        acc[m][n] = MFMA16(af[m], b1[n], acc[m][n]);
  }

  if constexpr(MODE==6){
    #pragma unroll
    for (int m=0;m<4;++m)
      #pragma unroll
      for (int np=0;np<2;++np)
        #pragma unroll
        for (int rr=0;rr<4;++rr){
          int row = wr + m*16 + lg*4 + rr;
          int gr = m0 + row;
          if (gr >= M) continue;
          float g = acc[m][2*np][rr];
          float u = acc[m][2*np+1][rr];
          float s = g/(1.f+__expf(-g))*u;
          int j = (wc>>1) + np*16 + lr;
          Cb[(long)(roff+gr)*ldcb + (col0>>1) + j] = f2bf(s);
        }
  } else {
    #pragma unroll
    for (int m=0;m<4;++m)
      #pragma unroll
      for (int n=0;n<4;++n)
        #pragma unroll
        for (int rr=0;rr<4;++rr){
          int row = wr + m*16 + lg*4 + rr;
          int gr = m0 + row;
          if (gr >= M) continue;
          int col = wc + n*16 + lr;
          float va = acc[m][n][rr];
          if constexpr(MODE==0){
            Cb[(long)(roff+gr)*ldcb + col0 + col] = f2bf(va);
          } else if constexpr(MODE==1){
            long idx = (long)gr*ldcf + col0 + col;
            Cf[idx] = resid[idx] + va*0.22f;
          } else if constexpr(MODE==5){
            float gt = gates[roff+gr];
            Cb[(long)(roff+gr)*ldcb + col0 + col] = f2bf(va*gt);
          }
        }
  }
}

//------------------------------------------------------------------
// MoE sum: out[t] += sum_{kk} part[inv[t*8+kk]]  (partials pre-scaled)
__global__ __launch_bounds__(192) void k_moesum(const u16* __restrict__ part,
    const int* __restrict__ inv, float* __restrict__ out)
{
  int t = blockIdx.x, tid = threadIdx.x;
  int c = tid*8;
  float s[8] = {0.f,0.f,0.f,0.f,0.f,0.f,0.f,0.f};
  #pragma unroll
  for (int kk=0;kk<8;++kk){
    int slot = inv[t*8+kk];
    short8 v = *(const short8*)&part[(long)slot*1536 + c];
    #pragma unroll
    for (int j=0;j<8;++j) s[j] += bf2f((u16)v[j]);
  }
  float* op = out + (long)t*1536 + c;
  f32x4 o0 = *(const f32x4*)op;
  f32x4 o1 = *(const f32x4*)(op+4);
  #pragma unroll
  for (int j=0;j<4;++j){ o0[j] += s[j]; o1[j] += s[j+4]; }
  *(f32x4*)op = o0;
  *(f32x4*)(op+4) = o1;
}

//------------------------------------------------------------------
// RoPE in-place on packed qkv [T][2560]: q = cols 0..1535, k = cols 1536..2047
__global__ __launch_bounds__(256) void k_rope(const int* __restrict__ pos,
    u16* __restrict__ qkvb)
{
  int gid = blockIdx.x*256 + threadIdx.x;
  int t = gid >> 10, p = gid & 1023;
  int j = p & 31;
  float invf = __expf(-(float)j * 0.28782313662425574f);
  float ang = (float)pos[t] * invf;
  float sn, cs; __sincosf(ang, &sn, &cs);
  u16* base;
  if (p < 768) base = qkvb + (long)t*2560 + (p>>5)*64;
  else         base = qkvb + (long)t*2560 + 1536 + ((p-768)>>5)*64;
  float x1 = bf2f(base[j]), x2 = bf2f(base[j+32]);
  base[j]    = f2bf(x1*cs - x2*sn);
  base[j+32] = f2bf(x2*cs + x1*sn);
}

//------------------------------------------------------------------
// Causal flash attention with KV-split (round-6 verbatim; qkv strides 2560).
// Block = (kvh, qt, chunk): qt<32 -> single chunk (direct write);
// qt>=32 -> chunk0 = kt 0..31, chunk1 = kt 32..qt, bf16 partials + (m,l).
__global__ __launch_bounds__(256,3) void k_attn(const u16* __restrict__ qg,
    const u16* __restrict__ kg, const u16* __restrict__ vT,
    u16* __restrict__ og, u16* __restrict__ Opart, float* __restrict__ mlb)
{
  int bid = blockIdx.x;               // 768 = 96 x 8
  int kvh = bid & 7;
  int ii = bid >> 3;
  int qt, kt0, kt1, chunk; bool single;
  if (ii < 32)      { qt = 32+ii;        chunk = 0; kt0 = 0;  kt1 = 32;   single = false; }
  else if (ii < 64) { qt = 63-(ii-32);   chunk = 1; kt0 = 32; kt1 = qt+1; single = false; }
  else              { qt = 31-(ii-64);   chunk = 0; kt0 = 0;  kt1 = qt+1; single = true;  }

  int tid = threadIdx.x, wv = tid>>6, lane = tid&63;
  int lr = lane&15, lg = lane>>4;
  __shared__ u16 Ksh[64*72];
  __shared__ u16 Vsh[64*72];
  __shared__ u16 Psh[4][16*72];
  int q0 = qt*64;
  int qrow = q0 + wv*16 + lr;
  short8 qf[3][2];
  #pragma unroll
  for (int hh=0;hh<3;++hh)
    #pragma unroll
    for (int c=0;c<2;++c)
      qf[hh][c] = *(const short8*)&qg[(long)qrow*2560 + (kvh*3+hh)*64 + c*32 + lg*8];

  float m_[3][4], l_[3][4];
  f32x4 Ot[3][4];
  #pragma unroll
  for (int hh=0;hh<3;++hh)
    #pragma unroll
    for (int r=0;r<4;++r){ m_[hh][r]=-1e30f; l_[hh][r]=0.f; }
  #pragma unroll
  for (int hh=0;hh<3;++hh)
    #pragma unroll
    for (int d=0;d<4;++d) Ot[hh][d]=(f32x4){0.f,0.f,0.f,0.f};

  int srow = tid>>3, sdc = (tid&7)*8;
  short8 kreg[2], vreg[2];
  auto loadKV = [&](int kt){
    #pragma unroll
    for (int i=0;i<2;++i){
      int row = srow + i*32;
      kreg[i] = *(const short8*)&kg[(long)(kt*64+row)*2560 + kvh*64 + sdc];
      vreg[i] = *(const short8*)&vT[(long)(kvh*64 + row)*4096 + kt*64 + sdc];
    }
  };
  loadKV(kt0);

  for (int kt=kt0; kt<kt1; ++kt){
    __syncthreads();
    #pragma unroll
    for (int i=0;i<2;++i){
      int row = srow + i*32;
      *(short8*)&Ksh[row*72 + sdc] = kreg[i];
      *(short8*)&Vsh[row*72 + sdc] = vreg[i];
    }
    __syncthreads();
    if (kt < kt1-1) loadKV(kt+1);
    bool diag = (kt==qt);

    #pragma unroll
    for (int hh=0;hh<3;++hh){
      f32x4 S[4];
      #pragma unroll
      for (int n=0;n<4;++n) S[n]=(f32x4){0.f,0.f,0.f,0.f};
      #pragma unroll
      for (int n=0;n<4;++n)
        #pragma unroll
        for (int c=0;c<2;++c){
          short8 kf = *(const short8*)&Ksh[(n*16+lr)*72 + c*32 + lg*8];
          S[n] = MFMA16(qf[hh][c], kf, S[n]);
        }

      float rmax[4] = {-1e30f,-1e30f,-1e30f,-1e30f};
      #pragma unroll
      for (int n=0;n<4;++n)
        #pragma unroll
        for (int r=0;r<4;++r){
          float sv = S[n][r]*0.015625f;
          if (diag){
            int colg = n*16 + lr;
            int rowg = wv*16 + lg*4 + r;
            if (colg > rowg) sv = -1e30f;
          }
          S[n][r] = sv;
          rmax[r] = fmaxf(rmax[r], sv);
        }
      #pragma unroll
      for (int r=0;r<4;++r) rmax[r] = red16_max(rmax[r]);

      float alpha[4], rsum[4];
      #pragma unroll
      for (int r=0;r<4;++r){
        float mn = fmaxf(m_[hh][r], rmax[r]);
        alpha[r] = __expf(m_[hh][r]-mn);
        m_[hh][r] = mn;
        rsum[r] = 0.f;
      }
      #pragma unroll
      for (int n=0;n<4;++n)
        #pragma unroll
        for (int r=0;r<4;++r){
          float pv = __expf(S[n][r]-m_[hh][r]);
          S[n][r]=pv; rsum[r]+=pv;
        }
      #pragma unroll
      for (int r=0;r<4;++r) rsum[r] = red16_sum(rsum[r]);
      #pragma unroll
      for (int r=0;r<4;++r) l_[hh][r] = l_[hh][r]*alpha[r] + rsum[r];
      #pragma unroll
      for (int d=0;d<4;++d)
        #pragma unroll
        for (int r=0;r<4;++r) Ot[hh][d][r] *= alpha[r];

      #pragma unroll
      for (int n=0;n<4;++n)
        #pragma unroll
        for (int r=0;r<4;++r)
          Psh[wv][(lg*4+r)*72 + n*16 + lr] = f2bf(S[n][r]);
      #pragma unroll
      for (int c=0;c<2;++c){
        short8 pf = *(const short8*)&Psh[wv][lr*72 + c*32 + lg*8];
        #pragma unroll
        for (int d=0;d<4;++d){
          short8 vf = *(const short8*)&Vsh[(d*16+lr)*72 + c*32 + lg*8];
          Ot[hh][d] = MFMA16(pf, vf, Ot[hh][d]);
        }
      }
    }
  }

  if (single){
    #pragma unroll
    for (int hh=0;hh<3;++hh)
      #pragma unroll
      for (int d=0;d<4;++d)
        #pragma unroll
        for (int r=0;r<4;++r){
          int t = q0 + wv*16 + lg*4 + r;
          og[(long)t*1536 + (kvh*3+hh)*64 + d*16 + lr] = f2bf(Ot[hh][d][r]/l_[hh][r]);
        }
  } else {
    #pragma unroll
    for (int hh=0;hh<3;++hh){
      int h = kvh*3+hh;
      #pragma unroll
      for (int r=0;r<4;++r){
        int t = q0 + wv*16 + lg*4 + r;
        long slot = ((long)(t-2048)*24 + h)*2 + chunk;
        #pragma unroll
        for (int d=0;d<4;++d)
          Opart[slot*64 + d*16 + lr] = f2bf(Ot[hh][d][r]);
        if (lr==0){ mlb[slot*2] = m_[hh][r]; mlb[slot*2+1] = l_[hh][r]; }
      }
    }
  }
}

//------------------------------------------------------------------
// Combine the two KV-split partials for t>=2048 (round-6 verbatim)
__global__ __launch_bounds__(256) void k_comb(const u16* __restrict__ Opart,
    const float* __restrict__ mlb, u16* __restrict__ og)
{
  int gid = blockIdx.x*256 + threadIdx.x;   // 2048*24*64
  int d = gid & 63;
  long rowi = gid >> 6;                      // t'*24 + h
  long s0 = rowi*2, s1 = s0+1;
  float m0 = mlb[s0*2], l0 = mlb[s0*2+1];
  float m1 = mlb[s1*2], l1 = mlb[s1*2+1];
  float M = fmaxf(m0,m1);
  float w0 = __expf(m0-M), w1 = __expf(m1-M);
  float o = (bf2f(Opart[s0*64+d])*w0 + bf2f(Opart[s1*64+d])*w1) / (l0*w0 + l1*w1);
  int t = 2048 + (int)(rowi/24), h = (int)(rowi - (rowi/24)*24);
  og[(long)t*1536 + h*64 + d] = f2bf(o);
}

//------------------------------------------------------------------
__global__ __launch_bounds__(64) void k_router(const u16* __restrict__ h2,
    const float* __restrict__ rw, int* __restrict__ topi, float* __restrict__ gatev)
{
  int t = blockIdx.x, lane = threadIdx.x;
  int e = lane & 31, hf = lane >> 5;
  const u16* hr = h2 + (size_t)t*1536 + hf*768;
  const float* wp = rw + (long)hf*768*32 + e;
  float s = 0.f;
  for (int d=0; d<768; ++d)
    s += bf2f(hr[d]) * wp[(long)d*32];
  s += __shfl_xor(s, 32);
  __shared__ float lgt[32];
  if (lane < 32) lgt[e] = s;
  __syncthreads();
  if (lane==0){
    u32 msk=0; float tv[8]; int ti[8];
    for (int kk=0;kk<8;++kk){
      float best=-1e30f; int bi=0;
      for (int j2=0;j2<32;++j2)
        if (!((msk>>j2)&1u) && lgt[j2] > best){ best=lgt[j2]; bi=j2; }
      msk |= 1u<<bi; tv[kk]=best; ti[kk]=bi;
    }
    float mx = tv[0], ssum = 0.f, ge[8];
    for (int kk=0;kk<8;++kk){ ge[kk]=__expf(tv[kk]-mx); ssum+=ge[kk]; }
    float isum = 1.f/ssum;
    for (int kk=0;kk<8;++kk){ topi[t*8+kk]=ti[kk]; gatev[t*8+kk]=ge[kk]*isum; }
  }
}

__global__ void k_hist(const int* __restrict__ topi, int* __restrict__ cnt){
  int i = blockIdx.x*256 + threadIdx.x;
  if (i < 4096*8) atomicAdd(&cnt[topi[i]], 1);
}
__global__ void k_scan(const int* __restrict__ cnt, int* __restrict__ offs, int* __restrict__ cur){
  if (threadIdx.x==0 && blockIdx.x==0){
    int a=0;
    for (int e2=0;e2<32;++e2){ offs[e2]=a; cur[e2]=a; a+=cnt[e2]; }
  }
}
__global__ void k_scatter(const int* __restrict__ topi, const float* __restrict__ gatev,
    int* __restrict__ cur, int* __restrict__ toks, float* __restrict__ gts,
    int* __restrict__ inv){
  int i = blockIdx.x*256 + threadIdx.x;
  if (i < 4096*8){
    int e2 = topi[i];
    int p = atomicAdd(&cur[e2], 1);
    toks[p] = i>>3;
    gts[p] = gatev[i]*0.22f;
    inv[i] = p;
  }
}

//------------------------------------------------------------------
extern "C" void kernel_launch(void* const* d_in, const int* in_sizes, int n_in,
                              void* d_out, int out_size, void* d_ws, size_t ws_size,
                              hipStream_t stream)
{
  const int*   positions = (const int*)  d_in[0];
  const float* hs   = (const float*)d_in[1];
  const float* ln1w = (const float*)d_in[2];
  const float* wq   = (const float*)d_in[3];
  const float* wk   = (const float*)d_in[4];
  const float* wv   = (const float*)d_in[5];
  const float* wo   = (const float*)d_in[6];
  const float* ln2w = (const float*)d_in[7];
  const float* rww  = (const float*)d_in[8];
  const float* wgu  = (const float*)d_in[9];
  const float* wdn  = (const float*)d_in[10];
  const float* sgu  = (const float*)d_in[11];
  const float* sdn  = (const float*)d_in[12];
  float* out = (float*)d_out;

  char* ws = (char*)d_ws;
  size_t off = 0;
  auto alloc = [&](size_t b)->void*{ void* p = ws + off; off += (b + 255) & ~(size_t)255; return p; };

  u16* hbf     = (u16*)alloc((size_t)4096*1536*2);   // ln1 out; attn partials; later h2
  u16* qkv     = (u16*)alloc((size_t)33554432);
  u16* qkvb = qkv;                                   // [4096][2560] packed q|k|v
  u16* aout = qkv + (size_t)4096*2560;               // [4096][1536]
  u16* act_moe = qkv;                                // 32768x512 bf16 overlays after o-proj
  u16* act_sh  = (u16*)alloc((size_t)4096*1024*2);   // also attn (m,l)
  u16* vT      = (u16*)alloc((size_t)8*64*4096*2);
  int*   topi  = (int*)  alloc(4096*8*4);
  float* gatev = (float*)alloc(4096*8*4);
  int*   toks  = (int*)  alloc(4096*8*4);
  float* gts   = (float*)alloc(4096*8*4);
  int*   inv   = (int*)  alloc(4096*8*4);
  int*   cnt   = (int*)  alloc(512);
  int*   offs  = (int*)  alloc(512);
  int*   cur   = (int*)  alloc(512);
  u16* wqkvT = (u16*)alloc((size_t)2560*1536*2);     // rows: 0-1535 wq, 1536-2047 wk, 2048-2559 wv
  u16* woT  = (u16*)alloc((size_t)1536*1536*2);
  u16* sguT = (u16*)alloc((size_t)2048*1536*2);
  u16* sdnT = (u16*)alloc((size_t)1536*1024*2);
  u16* wguT = (u16*)alloc((size_t)32*1024*1536*2);
  u16* wdnT = (u16*)alloc((size_t)32*1536*512*2);
  float* hidden2 = out;
  u16*   h2bf = hbf;
  u16*   Opart = hbf;            // dead between qkv-proj and ln2
  float* mlb   = (float*)act_sh; // dead until shared gate_up
  u16*   part  = wguT;           // dead after moe gate_up consumes it

  // 0. weight convert+transpose pre-pass (bf16, [N][K]); gate_up matrices interleaved
  k_wt <<<dim3(48,48,1), 256,0,stream>>>(wq,  wqkvT,               1536,1536, 0,0);
  k_wt <<<dim3(16,48,1), 256,0,stream>>>(wk,  wqkvT+(size_t)1536*1536, 1536,512, 0,0);
  k_wt <<<dim3(16,48,1), 256,0,stream>>>(wv,  wqkvT+(size_t)2048*1536, 1536,512, 0,0);
  k_wt <<<dim3(48,48,1), 256,0,stream>>>(wo,  woT,  1536,1536, 0,0);
  k_wti<<<dim3(64,48,1), 256,0,stream>>>(sgu, sguT, 1536,2048,1024, 0,0);
  k_wt <<<dim3(48,32,1), 256,0,stream>>>(sdn, sdnT, 1024,1536, 0,0);
  k_wti<<<dim3(32,48,32),256,0,stream>>>(wgu, wguT, 1536,1024,512, (long)1536*1024, (long)1536*1024);
  k_wt <<<dim3(48,16,32),256,0,stream>>>(wdn, wdnT, 512,1536,  (long)512*1536,  (long)512*1536);

  // 1. ln1
  k_rmsnorm<<<4096,192,0,stream>>>(hs, ln1w, hbf);
  // 2. fused q|k|v projection -> qkvb [4096][2560]
  k_gemm<0,0><<<dim3(20,32,1),256,0,stream>>>(hbf,1536, wqkvT,0,1536, 4096,nullptr,nullptr,nullptr,nullptr, qkvb,2560, nullptr,0, nullptr);
  // 5. rope (q,k in place), V transpose
  k_rope<<<16384,256,0,stream>>>(positions, qkvb);
  k_vt<<<dim3(64,8,1),256,0,stream>>>(qkvb + 2048, vT);
  // 6. flash attention with KV-split, then combine
  k_attn<<<dim3(768,1,1),256,0,stream>>>(qkvb, qkvb + 1536, vT, aout, Opart, mlb);
  k_comb<<<12288,256,0,stream>>>(Opart, mlb, aout);
  // 7. o-proj + residual -> hidden2 (in d_out)
  k_gemm<1,0><<<dim3(12,32,1),256,0,stream>>>(aout,1536, woT,0,1536, 4096,nullptr,nullptr,nullptr,nullptr, nullptr,0, hidden2,1536, hs);
  // 8. ln2
  k_rmsnorm<<<4096,192,0,stream>>>(hidden2, ln2w, h2bf);
  // 9. router + top-8
  k_router<<<4096,64,0,stream>>>(h2bf, rww, topi, gatev);
  // 10-13. expert grouping
  hipMemsetAsync(cnt, 0, 32*4, stream);
  k_hist<<<128,256,0,stream>>>(topi, cnt);
  k_scan<<<1,64,0,stream>>>(cnt, offs, cur);
  k_scatter<<<128,256,0,stream>>>(topi, gatev, cur, toks, gts, inv);
  // 14. moe gate_up + silu*mul (gathered rows, interleaved B)
  k_gemm<6,1><<<dim3(8,32,32),256,0,stream>>>(h2bf,1536, wguT,(long)1024*1536,1536, 0,cnt,offs,toks,nullptr, act_moe,512, nullptr,0, nullptr);
  // 15. shared gate_up + silu*mul (interleaved B)
  k_gemm<6,0><<<dim3(16,32,1),256,0,stream>>>(h2bf,1536, sguT,0,1536, 4096,nullptr,nullptr,nullptr,nullptr, act_sh,1024, nullptr,0, nullptr);
  // 16. shared down: out = hidden2 + shared*0.22
  k_gemm<1,0><<<dim3(12,32,1),256,0,stream>>>(act_sh,1024, sdnT,0,1024, 4096,nullptr,nullptr,nullptr,nullptr, nullptr,0, out,1536, out);
  // 17. moe down -> gate-scaled bf16 partials (overlaying dead wguT)
  k_gemm<5,0><<<dim3(12,32,32),256,0,stream>>>(act_moe,512, wdnT,(long)1536*512,512, 0,cnt,offs,nullptr,gts, part,1536, nullptr,0, nullptr);
  // 18. sum the 8 partials per token onto out
  k_moesum<<<4096,192,0,stream>>>(part, inv, out);

  (void)in_sizes; (void)n_in; (void)out_size; (void)ws_size;
}